// Round 3
// baseline (352.264 us; speedup 1.0000x reference)
//
#include <hip/hip_runtime.h>

#define B_    4
#define S_    2048
#define C_    768
#define AH    384
#define H_    6
#define D_    64
#define KK    9
#define NTOK  (B_*S_)
#define NW    1920   // q | k | v | conv_out | key_conv
#define NCK   (H_*KK)   // 54

typedef unsigned short u16;
typedef __attribute__((ext_vector_type(8))) short   bf16x8;
typedef __attribute__((ext_vector_type(4))) float   f32x4;
typedef __attribute__((ext_vector_type(8))) unsigned short us8;

__device__ __forceinline__ float bf2f(u16 u) {
    union { unsigned u; float f; } x; x.u = ((unsigned)u) << 16; return x.f;
}
__device__ __forceinline__ u16 f2bf(float f) {
    union { float f; unsigned u; } x; x.f = f;
    unsigned r = x.u + 0x7fff + ((x.u >> 16) & 1);
    return (u16)(r >> 16);
}
__device__ __forceinline__ float ldmix(const void* p, size_t i, int isf32) {
    return isf32 ? ((const float*)p)[i] : bf2f(((const u16*)p)[i]);
}
__device__ __forceinline__ void gload16(const u16* g, u16* l) {
    __builtin_amdgcn_global_load_lds(
        (const __attribute__((address_space(1))) unsigned int*)g,
        (__attribute__((address_space(3))) unsigned int*)l, 16, 0, 0);
}

// ---------------- dtype sniff: flag=1 if inputs are fp32, 0 if bf16
__global__ __launch_bounds__(1024) void sniff_kernel(const unsigned* __restrict__ h,
                                                     int* __restrict__ flag)
{
    __shared__ int cnt;
    if (threadIdx.x == 0) cnt = 0;
    __syncthreads();
    unsigned u = h[threadIdx.x];
    int e = (u >> 7) & 0xFF;           // bf16: exponent of low element; fp32: mantissa bits
    if (e >= 120 && e <= 134) atomicAdd(&cnt, 1);
    __syncthreads();
    if (threadIdx.x == 0) *flag = (cnt < 512) ? 1 : 0;
}

// ---------------- canonicalize: Hbf (bf16 hidden), dwkc, Wckc (bf16), bckc (f32)
__global__ __launch_bounds__(256) void canon_kernel(
    const void* __restrict__ hidden, const void* __restrict__ dwk,
    const void* __restrict__ Wck, const void* __restrict__ bck,
    const int* __restrict__ flag,
    u16* __restrict__ Hbf, u16* __restrict__ dwkc,
    u16* __restrict__ Wckc, float* __restrict__ bckc)
{
    int t = blockIdx.x * 256 + threadIdx.x;
    int isf32 = *flag;
    const int NH8 = NTOK * C_ / 8;     // 786432
    if (t < NH8) {
        us8 o;
        if (isf32) {
            const float* src = (const float*)hidden + (size_t)t * 8;
            for (int i = 0; i < 8; i++) o[i] = f2bf(src[i]);
        } else {
            o = *((const us8*)hidden + t);
        }
        *(us8*)&Hbf[(size_t)t * 8] = o;
        return;
    }
    int u = t - NH8;
    if (u < C_ * KK) { dwkc[u] = f2bf(ldmix(dwk, u, isf32)); return; }
    u -= C_ * KK;
    if (u < AH * NCK) { Wckc[u] = f2bf(ldmix(Wck, u, isf32)); return; }
    u -= AH * NCK;
    if (u < NCK) { bckc[u] = ldmix(bck, u, isf32); return; }
}

// ---------------- prep: WallT[1920][768] = [Wq|Wk|Wv|Wco]^T | pw ; bias_all[1920]
__global__ __launch_bounds__(256) void prep_kernel(
    const void* __restrict__ Wq, const void* __restrict__ Wk,
    const void* __restrict__ Wv, const void* __restrict__ Wco,
    const void* __restrict__ pw,
    const void* __restrict__ bq, const void* __restrict__ bk,
    const void* __restrict__ bv, const void* __restrict__ bco,
    const void* __restrict__ cb, const int* __restrict__ flag,
    u16* __restrict__ WallT, float* __restrict__ bias)
{
    int t = blockIdx.x * 256 + threadIdx.x;
    if (t >= NW * 96) return;
    int isf32 = *flag;
    int n = t / 96, k8 = t % 96;
    int g = n / AH, m = n % AH;
    us8 v;
    if (g < 4) {
        const void* W = (g == 0) ? Wq : (g == 1) ? Wk : (g == 2) ? Wv : Wco;
        for (int i = 0; i < 8; i++) v[i] = f2bf(ldmix(W, (size_t)(k8 * 8 + i) * AH + m, isf32));
    } else {
        for (int i = 0; i < 8; i++) v[i] = f2bf(ldmix(pw, (size_t)m * C_ + k8 * 8 + i, isf32));
    }
    *(us8*)&WallT[(size_t)n * C_ + k8 * 8] = v;
    if (k8 == 0) {
        const void* bs = (g == 0) ? bq : (g == 1) ? bk : (g == 2) ? bv : (g == 3) ? bco : cb;
        bias[n] = ldmix(bs, m, isf32);
    }
}

// ---------------- depthwise conv over seq: dwout[tok][c]  (canonical bf16 in/out)
__global__ __launch_bounds__(256) void dwconv_kernel(
    const u16* __restrict__ x, const u16* __restrict__ dwk, u16* __restrict__ dwout)
{
    int t = blockIdx.x * 256 + threadIdx.x;   // NTOK/8 * 96 = 98304 threads
    int cg = t % 96, u = t / 96;
    int b = u >> 8, s0 = (u & 255) << 3;
    int c0 = cg * 8;
    float wf[KK][8];
    for (int k = 0; k < KK; k++)
        for (int i = 0; i < 8; i++) wf[k][i] = bf2f(dwk[(c0 + i) * KK + k]);
    float acc[8][8];
    for (int s = 0; s < 8; s++) for (int i = 0; i < 8; i++) acc[s][i] = 0.f;
    for (int r = 0; r < 16; r++) {
        int ss = s0 + r - 4;
        if (ss < 0 || ss >= S_) continue;
        us8 xv = *(const us8*)&x[((size_t)(b * S_ + ss)) * C_ + c0];
        float xf[8];
        for (int i = 0; i < 8; i++) xf[i] = bf2f(xv[i]);
        for (int k = 0; k < KK; k++) {
            int so = r - k;
            if (so < 0 || so >= 8) continue;
            for (int i = 0; i < 8; i++) acc[so][i] += xf[i] * wf[k][i];
        }
    }
    for (int s = 0; s < 8; s++) {
        us8 o;
        for (int i = 0; i < 8; i++) o[i] = f2bf(acc[s][i]);
        *(us8*)&dwout[((size_t)(b * S_ + s0 + s)) * C_ + c0] = o;
    }
}

// ---------------- big GEMM: P[8192][1920] = A * WallT^T + bias  (A = Hbf or dwb)
__global__ __launch_bounds__(256) void gemm_kernel(
    const u16* __restrict__ hidden, const u16* __restrict__ dwb,
    const u16* __restrict__ WallT, const float* __restrict__ bias,
    u16* __restrict__ P)
{
    __shared__ __attribute__((aligned(16))) u16 As[128 * 64];
    __shared__ __attribute__((aligned(16))) u16 Bs[128 * 64];
    int bx = blockIdx.x;
    int tm = bx % 64, tn = bx / 64;
    const u16* A = (tn >= 12) ? dwb : hidden;
    int tid = threadIdx.x;
    int lane = tid & 63, wv = tid >> 6;
    int wm = wv >> 1, wn = wv & 1;
    int l15 = lane & 15, l4 = lane >> 4;
    int srow = lane >> 3, schunk = (lane & 7) * 8;
    f32x4 acc[4][4] = {};
    for (int kt = 0; kt < 12; ++kt) {
        __syncthreads();
        for (int c = 0; c < 4; c++) {
            int r = wv * 32 + c * 8;
            gload16(&A[(size_t)(tm * 128 + r + srow) * C_ + kt * 64 + schunk], &As[r * 64]);
            gload16(&WallT[(size_t)(tn * 128 + r + srow) * C_ + kt * 64 + schunk], &Bs[r * 64]);
        }
        asm volatile("s_waitcnt vmcnt(0)" ::: "memory");
        __syncthreads();
        for (int ks = 0; ks < 2; ++ks) {
            bf16x8 aF[4], bF[4];
            for (int mi = 0; mi < 4; mi++)
                aF[mi] = *(const bf16x8*)&As[(wm * 64 + mi * 16 + l15) * 64 + ks * 32 + l4 * 8];
            for (int ni = 0; ni < 4; ni++)
                bF[ni] = *(const bf16x8*)&Bs[(wn * 64 + ni * 16 + l15) * 64 + ks * 32 + l4 * 8];
            for (int mi = 0; mi < 4; mi++)
                for (int ni = 0; ni < 4; ni++)
                    acc[mi][ni] = __builtin_amdgcn_mfma_f32_16x16x32_bf16(
                        aF[mi], bF[ni], acc[mi][ni], 0, 0, 0);
        }
    }
    for (int mi = 0; mi < 4; mi++)
        for (int ni = 0; ni < 4; ni++)
            for (int j = 0; j < 4; j++) {
                int row = tm * 128 + wm * 64 + mi * 16 + l4 * 4 + j;
                int col = tn * 128 + wn * 64 + ni * 16 + l15;
                P[(size_t)row * NW + col] = f2bf(acc[mi][ni][j] + bias[col]);
            }
}

// ---------------- V transpose: Vt[bh][d][s]
__global__ __launch_bounds__(256) void vt_kernel(
    const u16* __restrict__ P, u16* __restrict__ Vt)
{
    int t = blockIdx.x * 256 + threadIdx.x;   // 24*64*256 = 393216
    int d = t & 63;
    int s8 = (t >> 6) & 255;
    int bh = t >> 14;
    int b = bh / H_, h = bh % H_;
    us8 o;
    for (int i = 0; i < 8; i++)
        o[i] = P[(size_t)(b * S_ + s8 * 8 + i) * NW + 2 * AH + h * D_ + d];
    *(us8*)&Vt[((size_t)bh * D_ + d) * S_ + s8 * 8] = o;
}

// ---------------- flash attention (swapped-operand MFMA)
__global__ __launch_bounds__(256) void flash_kernel(
    const u16* __restrict__ P, const u16* __restrict__ Vt,
    const void* __restrict__ mask, const int* __restrict__ flag,
    void* __restrict__ out)
{
    __shared__ __attribute__((aligned(16))) u16 Qs[64 * 64];
    __shared__ __attribute__((aligned(16))) u16 Ks[64 * 64];
    __shared__ __attribute__((aligned(16))) u16 Vts[64 * 64];
    __shared__ __attribute__((aligned(16))) u16 Ps[4][64 * 16];
    __shared__ float Ms[S_];
    const float LOG2E = 1.4426950408889634f;

    int qt = blockIdx.x, bh = blockIdx.y;
    int b = bh / H_, h = bh % H_;
    int tid = threadIdx.x, lane = tid & 63, wv = tid >> 6;
    int l15 = lane & 15, l4 = lane >> 4;
    int srow = lane >> 3, schunk = (lane & 7) * 8;
    int isf32 = *flag;

    for (int j = 0; j < 8; j++)        // stage mask -> f32
        Ms[tid * 8 + j] = ldmix(mask, (size_t)b * S_ + tid * 8 + j, isf32);
    for (int c = 0; c < 2; c++) {      // stage Q tile [64 q][64 d]
        int r = wv * 16 + c * 8;
        gload16(&P[(size_t)(b * S_ + qt * 64 + r + srow) * NW + h * D_ + schunk], &Qs[r * 64]);
    }
    asm volatile("s_waitcnt vmcnt(0)" ::: "memory");
    __syncthreads();
    bf16x8 qf[2];
    for (int ks = 0; ks < 2; ks++)
        qf[ks] = *(const bf16x8*)&Qs[(wv * 16 + l15) * 64 + ks * 32 + l4 * 8];

    f32x4 oacc[4] = {};
    float mrun = -INFINITY, lrun = 0.f;

    for (int kt = 0; kt < 32; ++kt) {
        __syncthreads();
        for (int c = 0; c < 2; c++) {
            int r = wv * 16 + c * 8;
            gload16(&P[(size_t)(b * S_ + kt * 64 + r + srow) * NW + AH + h * D_ + schunk], &Ks[r * 64]);
            gload16(&Vt[((size_t)bh * D_ + r + srow) * S_ + kt * 64 + schunk], &Vts[r * 64]);
        }
        asm volatile("s_waitcnt vmcnt(0)" ::: "memory");
        __syncthreads();

        // S^T = K * Q^T : lane holds S[key_local = kf*16 + l4*4 + j][q = l15]
        f32x4 sacc[4] = {};
        for (int ks = 0; ks < 2; ks++)
            for (int kf = 0; kf < 4; kf++) {
                bf16x8 aK = *(const bf16x8*)&Ks[(kf * 16 + l15) * 64 + ks * 32 + l4 * 8];
                sacc[kf] = __builtin_amdgcn_mfma_f32_16x16x32_bf16(aK, qf[ks], sacc[kf], 0, 0, 0);
            }

        float vals[4][4];
        float tmax = -INFINITY;
        for (int kf = 0; kf < 4; kf++)
            for (int j = 0; j < 4; j++) {
                float v = sacc[kf][j] * 0.125f + Ms[kt * 64 + kf * 16 + l4 * 4 + j];
                vals[kf][j] = v;
                tmax = fmaxf(tmax, v);
            }
        tmax = fmaxf(tmax, __shfl_xor(tmax, 16));
        tmax = fmaxf(tmax, __shfl_xor(tmax, 32));
        float mnew = fmaxf(mrun, tmax);
        float alpha = exp2f((mrun - mnew) * LOG2E);
        float ps = 0.f;
        for (int kf = 0; kf < 4; kf++)
            for (int j = 0; j < 4; j++) {
                float p = exp2f((vals[kf][j] - mnew) * LOG2E);
                ps += p;
                Ps[wv][(kf * 16 + l4 * 4 + j) * 16 + l15] = f2bf(p);
            }
        ps += __shfl_xor(ps, 16);
        ps += __shfl_xor(ps, 32);
        lrun = lrun * alpha + ps;
        mrun = mnew;
        for (int mf = 0; mf < 4; mf++) oacc[mf] *= alpha;

        // O^T += V^T * P^T : lane holds O[d = mf*16 + l4*4 + j][q = l15]
        for (int ks2 = 0; ks2 < 2; ks2++) {
            bf16x8 pf;
            for (int jj = 0; jj < 8; jj++)
                pf[jj] = (short)Ps[wv][(ks2 * 32 + l4 * 8 + jj) * 16 + l15];
            for (int mf = 0; mf < 4; mf++) {
                bf16x8 av = *(const bf16x8*)&Vts[(mf * 16 + l15) * 64 + ks2 * 32 + l4 * 8];
                oacc[mf] = __builtin_amdgcn_mfma_f32_16x16x32_bf16(av, pf, oacc[mf], 0, 0, 0);
            }
        }
    }
    float rinv = 1.0f / lrun;
    int tok = qt * 64 + wv * 16 + l15;
    for (int mf = 0; mf < 4; mf++)
        for (int j = 0; j < 4; j++) {
            int d = mf * 16 + l4 * 4 + j;
            size_t oi = (size_t)(b * S_ + tok) * C_ + h * D_ + d;
            float val = oacc[mf][j] * rinv;
            if (isf32) ((float*)out)[oi] = val; else ((u16*)out)[oi] = f2bf(val);
        }
}

// ---------------- dynamic conv branch: one block per token
__global__ __launch_bounds__(384) void dynk_kernel(
    const u16* __restrict__ P, const u16* __restrict__ Wckc,
    const float* __restrict__ bckc, const int* __restrict__ flag,
    void* __restrict__ out)
{
    __shared__ float ca[AH];
    __shared__ float lg[NCK];
    __shared__ float kr[NCK];
    int tok = blockIdx.x;
    int s = tok & (S_ - 1);
    int tid = threadIdx.x;
    int isf32 = *flag;
    float qv = bf2f(P[(size_t)tok * NW + tid]);
    float kc = bf2f(P[(size_t)tok * NW + 4 * AH + tid]);
    ca[tid] = qv * kc;
    __syncthreads();
    if (tid < NCK) {
        float acc = bckc[tid];
        for (int c = 0; c < AH; c++) acc += ca[c] * bf2f(Wckc[c * NCK + tid]);
        lg[tid] = acc;
    }
    __syncthreads();
    if (tid < H_) {
        float m = -INFINITY;
        for (int k = 0; k < KK; k++) m = fmaxf(m, lg[tid * KK + k]);
        float ssum = 0.f; float e[KK];
        for (int k = 0; k < KK; k++) {
            e[k] = exp2f((lg[tid * KK + k] - m) * 1.4426950408889634f);
            ssum += e[k];
        }
        for (int k = 0; k < KK; k++) kr[tid * KK + k] = e[k] / ssum;
    }
    __syncthreads();
    int hh = tid >> 6;
    float acc = 0.f;
    for (int k = 0; k < KK; k++) {
        int ss = s + k - 4;
        if (ss >= 0 && ss < S_)
            acc += kr[hh * KK + k] * bf2f(P[(size_t)(tok + k - 4) * NW + 3 * AH + tid]);
    }
    size_t oi = (size_t)tok * C_ + AH + tid;
    if (isf32) ((float*)out)[oi] = acc; else ((u16*)out)[oi] = f2bf(acc);
}

extern "C" void kernel_launch(void* const* d_in, const int* in_sizes, int n_in,
                              void* d_out, int out_size, void* d_ws, size_t ws_size,
                              hipStream_t stream) {
    const void* hidden = d_in[0];
    const void* mask   = d_in[1];
    const void* Wq  = d_in[2];
    const void* bq  = d_in[3];
    const void* Wk  = d_in[4];
    const void* bk  = d_in[5];
    const void* Wv  = d_in[6];
    const void* bv  = d_in[7];
    const void* dwk = d_in[8];
    const void* pw  = d_in[9];
    const void* cb  = d_in[10];
    const void* Wck = d_in[11];
    const void* bck = d_in[12];
    const void* Wco = d_in[13];
    const void* bco = d_in[14];
    char* ws = (char*)d_ws;

    // ws layout (16B-aligned offsets), total 65,926,928 bytes (~62.9 MiB)
    const size_t NEED = 65926928u;
    if (ws_size < NEED) return;   // deterministic; signals ws-too-small via untouched output

    u16*   Pbuf  = (u16*)(ws);                       // 31,457,280
    u16*   Hbf   = (u16*)(ws + 31457280);            // 12,582,912
    u16*   dwb   = (u16*)(ws + 44040192);            // 12,582,912
    u16*   WallT = (u16*)(ws + 56623104);            //  2,949,120
    float* bias  = (float*)(ws + 59572224);          //      7,680
    u16*   Vt    = (u16*)(ws + 59579904);            //  6,291,456
    u16*   dwkc  = (u16*)(ws + 65871360);            //     13,824
    u16*   Wckc  = (u16*)(ws + 65885184);            //     41,472
    float* bckc  = (float*)(ws + 65926656);          //        256
    int*   flag  = (int*)(ws + 65926912);            //         16

    sniff_kernel<<<1, 1024, 0, stream>>>((const unsigned*)hidden, flag);
    canon_kernel<<<3181, 256, 0, stream>>>(hidden, dwk, Wck, bck, flag, Hbf, dwkc, Wckc, bckc);
    prep_kernel<<<720, 256, 0, stream>>>(Wq, Wk, Wv, Wco, pw, bq, bk, bv, bco, cb, flag, WallT, bias);
    dwconv_kernel<<<384, 256, 0, stream>>>(Hbf, dwkc, dwb);
    gemm_kernel<<<960, 256, 0, stream>>>(Hbf, dwb, WallT, bias, Pbuf);
    vt_kernel<<<1536, 256, 0, stream>>>(Pbuf, Vt);
    flash_kernel<<<dim3(32, 24), 256, 0, stream>>>(Pbuf, Vt, mask, flag, d_out);
    dynk_kernel<<<8192, 384, 0, stream>>>(Pbuf, Wckc, bckc, flag, d_out);
}

// Round 4
// 321.548 us; speedup vs baseline: 1.0955x; 1.0955x over previous
//
#include <hip/hip_runtime.h>

#define B_    4
#define S_    2048
#define C_    768
#define AH    384
#define H_    6
#define D_    64
#define KK    9
#define NTOK  (B_*S_)
#define NW    1920   // q | k | v | conv_out | key_conv
#define NCK   (H_*KK)   // 54

typedef unsigned short u16;
typedef __attribute__((ext_vector_type(8))) short   bf16x8;
typedef __attribute__((ext_vector_type(4))) float   f32x4;
typedef __attribute__((ext_vector_type(4))) float   float4v;
typedef __attribute__((ext_vector_type(8))) unsigned short us8;

__device__ __forceinline__ float bf2f(u16 u) {
    union { unsigned u; float f; } x; x.u = ((unsigned)u) << 16; return x.f;
}
__device__ __forceinline__ u16 f2bf(float f) {
    union { float f; unsigned u; } x; x.f = f;
    unsigned r = x.u + 0x7fff + ((x.u >> 16) & 1);
    return (u16)(r >> 16);
}
__device__ __forceinline__ float ldmix(const void* p, size_t i, int isf32) {
    return isf32 ? ((const float*)p)[i] : bf2f(((const u16*)p)[i]);
}
__device__ __forceinline__ void gload16(const u16* g, u16* l) {
    __builtin_amdgcn_global_load_lds(
        (const __attribute__((address_space(1))) unsigned int*)g,
        (__attribute__((address_space(3))) unsigned int*)l, 16, 0, 0);
}
// swizzled-read index into a [rows][64 u16] LDS tile staged with pre-swizzled source:
// logical (row, 16B-chunk cb) lives at chunk cb ^ (row&7)
__device__ __forceinline__ int rc(int row, int cb) {
    return row * 64 + (((cb) ^ (row & 7)) << 3);
}

// ---------------- dtype sniff: flag=1 if inputs are fp32, 0 if bf16
__global__ __launch_bounds__(1024) void sniff_kernel(const unsigned* __restrict__ h,
                                                     int* __restrict__ flag)
{
    __shared__ int cnt;
    if (threadIdx.x == 0) cnt = 0;
    __syncthreads();
    unsigned u = h[threadIdx.x];
    int e = (u >> 7) & 0xFF;
    if (e >= 120 && e <= 134) atomicAdd(&cnt, 1);
    __syncthreads();
    if (threadIdx.x == 0) *flag = (cnt < 512) ? 1 : 0;
}

// ---------------- canonicalize small tensors: dwkc, Wckc (bf16), bckc (f32)
__global__ __launch_bounds__(256) void canon_kernel(
    const void* __restrict__ dwk, const void* __restrict__ Wck,
    const void* __restrict__ bck, const int* __restrict__ flag,
    u16* __restrict__ dwkc, u16* __restrict__ Wckc, float* __restrict__ bckc)
{
    int t = blockIdx.x * 256 + threadIdx.x;
    int isf32 = *flag;
    if (t < C_ * KK) { dwkc[t] = f2bf(ldmix(dwk, t, isf32)); return; }
    int u = t - C_ * KK;
    if (u < AH * NCK) { Wckc[u] = f2bf(ldmix(Wck, u, isf32)); return; }
    u -= AH * NCK;
    if (u < NCK) { bckc[u] = ldmix(bck, u, isf32); return; }
}

// ---------------- prep: WallT[1920][768] = [Wq|Wk|Wv|Wco]^T | pw ; bias_all[1920]
__global__ __launch_bounds__(256) void prep_kernel(
    const void* __restrict__ Wq, const void* __restrict__ Wk,
    const void* __restrict__ Wv, const void* __restrict__ Wco,
    const void* __restrict__ pw,
    const void* __restrict__ bq, const void* __restrict__ bk,
    const void* __restrict__ bv, const void* __restrict__ bco,
    const void* __restrict__ cb, const int* __restrict__ flag,
    u16* __restrict__ WallT, float* __restrict__ bias)
{
    int t = blockIdx.x * 256 + threadIdx.x;
    if (t >= NW * 96) return;
    int isf32 = *flag;
    int n = t / 96, k8 = t % 96;
    int g = n / AH, m = n % AH;
    us8 v;
    if (g < 4) {
        const void* W = (g == 0) ? Wq : (g == 1) ? Wk : (g == 2) ? Wv : Wco;
        for (int i = 0; i < 8; i++) v[i] = f2bf(ldmix(W, (size_t)(k8 * 8 + i) * AH + m, isf32));
    } else {
        for (int i = 0; i < 8; i++) v[i] = f2bf(ldmix(pw, (size_t)m * C_ + k8 * 8 + i, isf32));
    }
    *(us8*)&WallT[(size_t)n * C_ + k8 * 8] = v;
    if (k8 == 0) {
        const void* bs = (g == 0) ? bq : (g == 1) ? bk : (g == 2) ? bv : (g == 3) ? bco : cb;
        bias[n] = ldmix(bs, m, isf32);
    }
}

// ---------------- depthwise conv + Hbf production (reads raw hidden)
__global__ __launch_bounds__(256) void dwconv_kernel(
    const void* __restrict__ x, const u16* __restrict__ dwkc,
    const int* __restrict__ flag, u16* __restrict__ Hbf, u16* __restrict__ dwout)
{
    int t = blockIdx.x * 256 + threadIdx.x;   // 98304 threads
    int isf32 = *flag;
    int cg = t % 96, u = t / 96;
    int b = u >> 8, s0 = (u & 255) << 3;
    int c0 = cg * 8;
    float wf[KK][8];
    for (int k = 0; k < KK; k++)
        for (int i = 0; i < 8; i++) wf[k][i] = bf2f(dwkc[(c0 + i) * KK + k]);
    float acc[8][8];
    for (int s = 0; s < 8; s++) for (int i = 0; i < 8; i++) acc[s][i] = 0.f;
    for (int r = 0; r < 16; r++) {
        int ss = s0 + r - 4;
        if (ss < 0 || ss >= S_) continue;
        float xf[8];
        size_t base = ((size_t)(b * S_ + ss)) * C_ + c0;
        if (isf32) {
            float4v v0 = *(const float4v*)((const float*)x + base);
            float4v v1 = *(const float4v*)((const float*)x + base + 4);
            for (int i = 0; i < 4; i++) { xf[i] = v0[i]; xf[4 + i] = v1[i]; }
        } else {
            us8 xv = *(const us8*)((const u16*)x + base);
            for (int i = 0; i < 8; i++) xf[i] = bf2f(xv[i]);
        }
        if (r >= 4 && r < 12) {   // own rows: emit canonical bf16 hidden
            us8 o;
            for (int i = 0; i < 8; i++) o[i] = f2bf(xf[i]);
            *(us8*)&Hbf[base] = o;
        }
        for (int k = 0; k < KK; k++) {
            int so = r - k;
            if (so < 0 || so >= 8) continue;
            for (int i = 0; i < 8; i++) acc[so][i] += xf[i] * wf[k][i];
        }
    }
    for (int s = 0; s < 8; s++) {
        us8 o;
        for (int i = 0; i < 8; i++) o[i] = f2bf(acc[s][i]);
        *(us8*)&dwout[((size_t)(b * S_ + s0 + s)) * C_ + c0] = o;
    }
}

// ---------------- big GEMM: P[8192][1920] = A * WallT^T + bias  (swizzled LDS)
__global__ __launch_bounds__(256) void gemm_kernel(
    const u16* __restrict__ hidden, const u16* __restrict__ dwb,
    const u16* __restrict__ WallT, const float* __restrict__ bias,
    u16* __restrict__ P)
{
    __shared__ __attribute__((aligned(16))) u16 As[128 * 64];
    __shared__ __attribute__((aligned(16))) u16 Bs[128 * 64];
    int bx = blockIdx.x;
    int tm = bx % 64, tn = bx / 64;
    const u16* A = (tn >= 12) ? dwb : hidden;
    int tid = threadIdx.x;
    int lane = tid & 63, wv = tid >> 6;
    int wm = wv >> 1, wn = wv & 1;
    int l15 = lane & 15, l4 = lane >> 4;
    int srow = lane >> 3;
    int swz = (((lane & 7) ^ (lane >> 3)) & 7) * 8;   // pre-swizzled source chunk
    f32x4 acc[4][4] = {};
    for (int kt = 0; kt < 12; ++kt) {
        __syncthreads();
        for (int c = 0; c < 4; c++) {
            int r = wv * 32 + c * 8;
            gload16(&A[(size_t)(tm * 128 + r + srow) * C_ + kt * 64 + swz], &As[r * 64]);
            gload16(&WallT[(size_t)(tn * 128 + r + srow) * C_ + kt * 64 + swz], &Bs[r * 64]);
        }
        asm volatile("s_waitcnt vmcnt(0)" ::: "memory");
        __syncthreads();
        for (int ks = 0; ks < 2; ++ks) {
            bf16x8 aF[4], bF[4];
            for (int mi = 0; mi < 4; mi++)
                aF[mi] = *(const bf16x8*)&As[rc(wm * 64 + mi * 16 + l15, ks * 4 + l4)];
            for (int ni = 0; ni < 4; ni++)
                bF[ni] = *(const bf16x8*)&Bs[rc(wn * 64 + ni * 16 + l15, ks * 4 + l4)];
            for (int mi = 0; mi < 4; mi++)
                for (int ni = 0; ni < 4; ni++)
                    acc[mi][ni] = __builtin_amdgcn_mfma_f32_16x16x32_bf16(
                        aF[mi], bF[ni], acc[mi][ni], 0, 0, 0);
        }
    }
    for (int mi = 0; mi < 4; mi++)
        for (int ni = 0; ni < 4; ni++)
            for (int j = 0; j < 4; j++) {
                int row = tm * 128 + wm * 64 + mi * 16 + l4 * 4 + j;
                int col = tn * 128 + wn * 64 + ni * 16 + l15;
                P[(size_t)row * NW + col] = f2bf(acc[mi][ni][j] + bias[col]);
            }
}

// ---------------- V transpose via LDS tile: Vt[bh][d][s]
__global__ __launch_bounds__(256) void vt_kernel(
    const u16* __restrict__ P, u16* __restrict__ Vt)
{
    __shared__ u16 T[64][72];
    int st = blockIdx.x, bh = blockIdx.y;
    int b = bh / H_, h = bh % H_;
    int tid = threadIdx.x;
    for (int p = 0; p < 2; p++) {
        int row = p * 32 + (tid >> 3);
        int cd = (tid & 7) * 8;
        us8 v = *(const us8*)&P[(size_t)(b * S_ + st * 64 + row) * NW + 2 * AH + h * D_ + cd];
        *(us8*)&T[row][cd] = v;
    }
    __syncthreads();
    int d = tid & 63, sg = tid >> 6;
    for (int part = 0; part < 2; part++) {
        int sl = sg * 16 + part * 8;
        us8 o;
        for (int i = 0; i < 8; i++) o[i] = T[sl + i][d];
        *(us8*)&Vt[((size_t)bh * D_ + d) * S_ + st * 64 + sl] = o;
    }
}

// ---------------- flash attention (swizzled LDS, packed P, defer-max)
__global__ __launch_bounds__(256) void flash_kernel(
    const u16* __restrict__ P, const u16* __restrict__ Vt,
    const void* __restrict__ mask, const int* __restrict__ flag,
    void* __restrict__ out)
{
    __shared__ __attribute__((aligned(16))) u16 Qs[64 * 64];
    __shared__ __attribute__((aligned(16))) u16 Ks[64 * 64];
    __shared__ __attribute__((aligned(16))) u16 Vts[64 * 64];
    __shared__ __attribute__((aligned(16))) unsigned PpS[4 * 576]; // [wave][l15*36 + kpair]
    __shared__ float Ms[S_];
    const float LOG2E = 1.4426950408889634f;

    int qt = blockIdx.x, bh = blockIdx.y;
    int b = bh / H_, h = bh % H_;
    int tid = threadIdx.x, lane = tid & 63, wvid = tid >> 6;
    int l15 = lane & 15, l4 = lane >> 4;
    int srow = lane >> 3;
    int swz = (((lane & 7) ^ (lane >> 3)) & 7) * 8;
    int isf32 = *flag;
    unsigned* Pw = &PpS[wvid * 576];

    for (int j = 0; j < 8; j++)
        Ms[tid * 8 + j] = ldmix(mask, (size_t)b * S_ + tid * 8 + j, isf32);
    for (int c = 0; c < 2; c++) {
        int r = wvid * 16 + c * 8;
        gload16(&P[(size_t)(b * S_ + qt * 64 + r + srow) * NW + h * D_ + swz], &Qs[r * 64]);
    }
    asm volatile("s_waitcnt vmcnt(0)" ::: "memory");
    __syncthreads();
    bf16x8 qf[2];
    for (int ks = 0; ks < 2; ks++)
        qf[ks] = *(const bf16x8*)&Qs[rc(wvid * 16 + l15, ks * 4 + l4)];

    f32x4 oacc[4] = {};
    float mrun = -INFINITY, lrun = 0.f;

    for (int kt = 0; kt < 32; ++kt) {
        __syncthreads();
        for (int c = 0; c < 2; c++) {
            int r = wvid * 16 + c * 8;
            gload16(&P[(size_t)(b * S_ + kt * 64 + r + srow) * NW + AH + h * D_ + swz], &Ks[r * 64]);
            gload16(&Vt[((size_t)bh * D_ + r + srow) * S_ + kt * 64 + swz], &Vts[r * 64]);
        }
        asm volatile("s_waitcnt vmcnt(0)" ::: "memory");
        __syncthreads();

        // S^T = K * Q^T : lane holds S[key = kf*16 + l4*4 + j][q = l15]
        f32x4 sacc[4] = {};
        for (int ks = 0; ks < 2; ks++)
            for (int kf = 0; kf < 4; kf++) {
                bf16x8 aK = *(const bf16x8*)&Ks[rc(kf * 16 + l15, ks * 4 + l4)];
                sacc[kf] = __builtin_amdgcn_mfma_f32_16x16x32_bf16(aK, qf[ks], sacc[kf], 0, 0, 0);
            }

        float vals[4][4];
        float tmax = -INFINITY;
        for (int kf = 0; kf < 4; kf++)
            for (int j = 0; j < 4; j++) {
                float v = fmaf(sacc[kf][j], 0.125f, Ms[kt * 64 + kf * 16 + l4 * 4 + j]);
                vals[kf][j] = v;
                tmax = fmaxf(tmax, v);
            }
        tmax = fmaxf(tmax, __shfl_xor(tmax, 16));
        tmax = fmaxf(tmax, __shfl_xor(tmax, 32));
        if (!__all(tmax - mrun <= 8.0f)) {      // defer-max (THR=8)
            float mnew = fmaxf(mrun, tmax);
            float alpha = exp2f((mrun - mnew) * LOG2E);
            lrun *= alpha;
            for (int mf = 0; mf < 4; mf++) oacc[mf] *= alpha;
            mrun = mnew;
        }
        float ps = 0.f;
        for (int kf = 0; kf < 4; kf++) {
            float p0 = exp2f((vals[kf][0] - mrun) * LOG2E);
            float p1 = exp2f((vals[kf][1] - mrun) * LOG2E);
            float p2 = exp2f((vals[kf][2] - mrun) * LOG2E);
            float p3 = exp2f((vals[kf][3] - mrun) * LOG2E);
            ps += (p0 + p1) + (p2 + p3);
            union { float f; unsigned u; } b0{p0}, b1{p1}, b2{p2}, b3{p3};
            unsigned w0 = (b0.u >> 16) | (b1.u & 0xffff0000u);
            unsigned w1 = (b2.u >> 16) | (b3.u & 0xffff0000u);
            unsigned idx = l15 * 36 + kf * 8 + l4 * 2;
            Pw[idx] = w0;
            Pw[idx + 1] = w1;
        }
        ps += __shfl_xor(ps, 16);
        ps += __shfl_xor(ps, 32);
        lrun += ps;
        asm volatile("s_waitcnt lgkmcnt(0)" ::: "memory");
        __builtin_amdgcn_sched_barrier(0);

        // O^T += V^T * P^T : lane holds O[d = mf*16 + l4*4 + j][q = l15]
        for (int ks2 = 0; ks2 < 2; ks2++) {
            bf16x8 pf = *(const bf16x8*)&Pw[l15 * 36 + ks2 * 16 + l4 * 4];
            for (int mf = 0; mf < 4; mf++) {
                bf16x8 av = *(const bf16x8*)&Vts[rc(mf * 16 + l15, ks2 * 4 + l4)];
                oacc[mf] = __builtin_amdgcn_mfma_f32_16x16x32_bf16(av, pf, oacc[mf], 0, 0, 0);
            }
        }
    }
    float rinv = 1.0f / lrun;
    int tok = qt * 64 + wvid * 16 + l15;
    for (int mf = 0; mf < 4; mf++)
        for (int j = 0; j < 4; j++) {
            int d = mf * 16 + l4 * 4 + j;
            size_t oi = (size_t)(b * S_ + tok) * C_ + h * D_ + d;
            float val = oacc[mf][j] * rinv;
            if (isf32) ((float*)out)[oi] = val; else ((u16*)out)[oi] = f2bf(val);
        }
}

// ---------------- dynamic conv branch: one block per token, wave-parallel
__global__ __launch_bounds__(384) void dynk_kernel(
    const u16* __restrict__ P, const u16* __restrict__ Wckc,
    const float* __restrict__ bckc, const int* __restrict__ flag,
    void* __restrict__ out)
{
    __shared__ float ca[AH];
    __shared__ float lg[64];
    __shared__ float kr[64];
    int tok = blockIdx.x;
    int s = tok & (S_ - 1);
    int tid = threadIdx.x;
    int isf32 = *flag;
    float qv = bf2f(P[(size_t)tok * NW + tid]);
    float kc = bf2f(P[(size_t)tok * NW + 4 * AH + tid]);
    ca[tid] = qv * kc;
    __syncthreads();
    {   // wave w computes logits o = w*9 .. w*9+8
        int w = tid >> 6, lane = tid & 63;
        float part[9];
        #pragma unroll
        for (int o = 0; o < 9; o++) part[o] = 0.f;
        #pragma unroll
        for (int i = 0; i < 6; i++) {
            int c = i * 64 + lane;
            float cav = ca[c];
            #pragma unroll
            for (int o = 0; o < 9; o++)
                part[o] += cav * bf2f(Wckc[c * NCK + w * 9 + o]);
        }
        #pragma unroll
        for (int o = 0; o < 9; o++) {
            #pragma unroll
            for (int off = 32; off >= 1; off >>= 1)
                part[o] += __shfl_xor(part[o], off);
        }
        if (lane == 0) {
            #pragma unroll
            for (int o = 0; o < 9; o++) lg[w * 9 + o] = part[o] + bckc[w * 9 + o];
        }
    }
    __syncthreads();
    if (tid < H_) {
        float m = -INFINITY;
        for (int k = 0; k < KK; k++) m = fmaxf(m, lg[tid * KK + k]);
        float ssum = 0.f; float e[KK];
        for (int k = 0; k < KK; k++) {
            e[k] = exp2f((lg[tid * KK + k] - m) * 1.4426950408889634f);
            ssum += e[k];
        }
        for (int k = 0; k < KK; k++) kr[tid * KK + k] = e[k] / ssum;
    }
    __syncthreads();
    int hh = tid >> 6;
    float acc = 0.f;
    for (int k = 0; k < KK; k++) {
        int ss = s + k - 4;
        if (ss >= 0 && ss < S_)
            acc += kr[hh * KK + k] * bf2f(P[(size_t)(tok + k - 4) * NW + 3 * AH + tid]);
    }
    size_t oi = (size_t)tok * C_ + AH + tid;
    if (isf32) ((float*)out)[oi] = acc; else ((u16*)out)[oi] = f2bf(acc);
}

extern "C" void kernel_launch(void* const* d_in, const int* in_sizes, int n_in,
                              void* d_out, int out_size, void* d_ws, size_t ws_size,
                              hipStream_t stream) {
    const void* hidden = d_in[0];
    const void* mask   = d_in[1];
    const void* Wq  = d_in[2];
    const void* bq  = d_in[3];
    const void* Wk  = d_in[4];
    const void* bk  = d_in[5];
    const void* Wv  = d_in[6];
    const void* bv  = d_in[7];
    const void* dwk = d_in[8];
    const void* pw  = d_in[9];
    const void* cb  = d_in[10];
    const void* Wck = d_in[11];
    const void* bck = d_in[12];
    const void* Wco = d_in[13];
    const void* bco = d_in[14];
    char* ws = (char*)d_ws;

    const size_t NEED = 65926928u;
    if (ws_size < NEED) return;

    u16*   Pbuf  = (u16*)(ws);                       // 31,457,280
    u16*   Hbf   = (u16*)(ws + 31457280);            // 12,582,912
    u16*   dwb   = (u16*)(ws + 44040192);            // 12,582,912
    u16*   WallT = (u16*)(ws + 56623104);            //  2,949,120
    float* bias  = (float*)(ws + 59572224);          //      7,680
    u16*   Vt    = (u16*)(ws + 59579904);            //  6,291,456
    u16*   dwkc  = (u16*)(ws + 65871360);            //     13,824
    u16*   Wckc  = (u16*)(ws + 65885184);            //     41,472
    float* bckc  = (float*)(ws + 65926656);          //        256
    int*   flag  = (int*)(ws + 65926912);            //         16

    sniff_kernel<<<1, 1024, 0, stream>>>((const unsigned*)hidden, flag);
    canon_kernel<<<109, 256, 0, stream>>>(dwk, Wck, bck, flag, dwkc, Wckc, bckc);
    prep_kernel<<<720, 256, 0, stream>>>(Wq, Wk, Wv, Wco, pw, bq, bk, bv, bco, cb, flag, WallT, bias);
    dwconv_kernel<<<384, 256, 0, stream>>>(hidden, dwkc, flag, Hbf, dwb);
    gemm_kernel<<<960, 256, 0, stream>>>(Hbf, dwb, WallT, bias, Pbuf);
    vt_kernel<<<dim3(32, 24), 256, 0, stream>>>(Pbuf, Vt);
    flash_kernel<<<dim3(32, 24), 256, 0, stream>>>(Pbuf, Vt, mask, flag, d_out);
    dynk_kernel<<<8192, 384, 0, stream>>>(Pbuf, Wckc, bckc, flag, d_out);
}

// Round 9
// 255.914 us; speedup vs baseline: 1.3765x; 1.2565x over previous
//
#include <hip/hip_runtime.h>

#define B_    4
#define S_    2048
#define C_    768
#define AH    384
#define H_    6
#define D_    64
#define KK    9
#define NTOK  (B_*S_)
#define NW    1920   // q | k | v | conv_out | key_conv
#define NCK   (H_*KK)   // 54

typedef unsigned short u16;
typedef __attribute__((ext_vector_type(8))) short   bf16x8;
typedef __attribute__((ext_vector_type(4))) float   f32x4;
typedef __attribute__((ext_vector_type(4))) float   float4v;
typedef __attribute__((ext_vector_type(8))) unsigned short us8;

__device__ __forceinline__ float bf2f(u16 u) {
    union { unsigned u; float f; } x; x.u = ((unsigned)u) << 16; return x.f;
}
__device__ __forceinline__ u16 f2bf(float f) {
    union { float f; unsigned u; } x; x.f = f;
    unsigned r = x.u + 0x7fff + ((x.u >> 16) & 1);
    return (u16)(r >> 16);
}
__device__ __forceinline__ float ldmix(const void* p, size_t i, int isf32) {
    return isf32 ? ((const float*)p)[i] : bf2f(((const u16*)p)[i]);
}
__device__ __forceinline__ void gload16(const u16* g, u16* l) {
    __builtin_amdgcn_global_load_lds(
        (const __attribute__((address_space(1))) unsigned int*)g,
        (__attribute__((address_space(3))) unsigned int*)l, 16, 0, 0);
}
// swizzled-read index into a [rows][64 u16] LDS tile staged with pre-swizzled source:
// logical (row, 16B-chunk cb) lives at chunk cb ^ (row&7)
__device__ __forceinline__ int rc(int row, int cb) {
    return row * 64 + (((cb) ^ (row & 7)) << 3);
}

// ---------------- dtype sniff: flag=1 if inputs are fp32, 0 if bf16
__global__ __launch_bounds__(1024) void sniff_kernel(const unsigned* __restrict__ h,
                                                     int* __restrict__ flag)
{
    __shared__ int cnt;
    if (threadIdx.x == 0) cnt = 0;
    __syncthreads();
    unsigned u = h[threadIdx.x];
    int e = (u >> 7) & 0xFF;
    if (e >= 120 && e <= 134) atomicAdd(&cnt, 1);
    __syncthreads();
    if (threadIdx.x == 0) *flag = (cnt < 512) ? 1 : 0;
}

// ---------------- canonicalize small tensors: dwkc (bf16), WckT[64][AH] (bf16, padded), bckc (f32)
__global__ __launch_bounds__(256) void canon_kernel(
    const void* __restrict__ dwk, const void* __restrict__ Wck,
    const void* __restrict__ bck, const int* __restrict__ flag,
    u16* __restrict__ dwkc, u16* __restrict__ WckT, float* __restrict__ bckc)
{
    int t = blockIdx.x * 256 + threadIdx.x;
    int isf32 = *flag;
    if (t < C_ * KK) { dwkc[t] = f2bf(ldmix(dwk, t, isf32)); return; }
    int u = t - C_ * KK;
    if (u < 64 * AH) {   // WckT[o][c] = Wck[c][o], zero-padded rows 54..63; K-stride = AH
        int o = u / AH, c = u % AH;
        WckT[u] = (o < NCK) ? f2bf(ldmix(Wck, (size_t)c * NCK + o, isf32)) : (u16)0;
        return;
    }
    u -= 64 * AH;
    if (u < NCK) { bckc[u] = ldmix(bck, u, isf32); return; }
}

// ---------------- prep: WallT[1920][768] = [Wq|Wk|Wv|Wco]^T | pw ; bias_all[1920]
__global__ __launch_bounds__(256) void prep_kernel(
    const void* __restrict__ Wq, const void* __restrict__ Wk,
    const void* __restrict__ Wv, const void* __restrict__ Wco,
    const void* __restrict__ pw,
    const void* __restrict__ bq, const void* __restrict__ bk,
    const void* __restrict__ bv, const void* __restrict__ bco,
    const void* __restrict__ cb, const int* __restrict__ flag,
    u16* __restrict__ WallT, float* __restrict__ bias)
{
    int t = blockIdx.x * 256 + threadIdx.x;
    if (t >= NW * 96) return;
    int isf32 = *flag;
    int n = t / 96, k8 = t % 96;
    int g = n / AH, m = n % AH;
    us8 v;
    if (g < 4) {
        const void* W = (g == 0) ? Wq : (g == 1) ? Wk : (g == 2) ? Wv : Wco;
        for (int i = 0; i < 8; i++) v[i] = f2bf(ldmix(W, (size_t)(k8 * 8 + i) * AH + m, isf32));
    } else {
        for (int i = 0; i < 8; i++) v[i] = f2bf(ldmix(pw, (size_t)m * C_ + k8 * 8 + i, isf32));
    }
    *(us8*)&WallT[(size_t)n * C_ + k8 * 8] = v;
    if (k8 == 0) {
        const void* bs = (g == 0) ? bq : (g == 1) ? bk : (g == 2) ? bv : (g == 3) ? bco : cb;
        bias[n] = ldmix(bs, m, isf32);
    }
}

// ---------------- depthwise conv + Hbf production (reads raw hidden)
__global__ __launch_bounds__(256) void dwconv_kernel(
    const void* __restrict__ x, const u16* __restrict__ dwkc,
    const int* __restrict__ flag, u16* __restrict__ Hbf, u16* __restrict__ dwout)
{
    int t = blockIdx.x * 256 + threadIdx.x;   // 98304 threads
    int isf32 = *flag;
    int cg = t % 96, u = t / 96;
    int b = u >> 8, s0 = (u & 255) << 3;
    int c0 = cg * 8;
    float wf[KK][8];
    for (int k = 0; k < KK; k++)
        for (int i = 0; i < 8; i++) wf[k][i] = bf2f(dwkc[(c0 + i) * KK + k]);
    float acc[8][8];
    for (int s = 0; s < 8; s++) for (int i = 0; i < 8; i++) acc[s][i] = 0.f;
    for (int r = 0; r < 16; r++) {
        int ss = s0 + r - 4;
        if (ss < 0 || ss >= S_) continue;
        float xf[8];
        size_t base = ((size_t)(b * S_ + ss)) * C_ + c0;
        if (isf32) {
            float4v v0 = *(const float4v*)((const float*)x + base);
            float4v v1 = *(const float4v*)((const float*)x + base + 4);
            for (int i = 0; i < 4; i++) { xf[i] = v0[i]; xf[4 + i] = v1[i]; }
        } else {
            us8 xv = *(const us8*)((const u16*)x + base);
            for (int i = 0; i < 8; i++) xf[i] = bf2f(xv[i]);
        }
        if (r >= 4 && r < 12) {
            us8 o;
            for (int i = 0; i < 8; i++) o[i] = f2bf(xf[i]);
            *(us8*)&Hbf[base] = o;
        }
        for (int k = 0; k < KK; k++) {
            int so = r - k;
            if (so < 0 || so >= 8) continue;
            for (int i = 0; i < 8; i++) acc[so][i] += xf[i] * wf[k][i];
        }
    }
    for (int s = 0; s < 8; s++) {
        us8 o;
        for (int i = 0; i < 8; i++) o[i] = f2bf(acc[s][i]);
        *(us8*)&dwout[((size_t)(b * S_ + s0 + s)) * C_ + c0] = o;
    }
}

// ---------------- big GEMM: P[8192][1920] = A * WallT^T + bias  (swizzled LDS)
__global__ __launch_bounds__(256) void gemm_kernel(
    const u16* __restrict__ hidden, const u16* __restrict__ dwb,
    const u16* __restrict__ WallT, const float* __restrict__ bias,
    u16* __restrict__ P)
{
    __shared__ __attribute__((aligned(16))) u16 As[128 * 64];
    __shared__ __attribute__((aligned(16))) u16 Bs[128 * 64];
    int bx = blockIdx.x;
    int tm = bx % 64, tn = bx / 64;
    const u16* A = (tn >= 12) ? dwb : hidden;
    int tid = threadIdx.x;
    int lane = tid & 63, wv = tid >> 6;
    int wm = wv >> 1, wn = wv & 1;
    int l15 = lane & 15, l4 = lane >> 4;
    int srow = lane >> 3;
    int swz = (((lane & 7) ^ (lane >> 3)) & 7) * 8;
    f32x4 acc[4][4] = {};
    for (int kt = 0; kt < 12; ++kt) {
        __syncthreads();
        for (int c = 0; c < 4; c++) {
            int r = wv * 32 + c * 8;
            gload16(&A[(size_t)(tm * 128 + r + srow) * C_ + kt * 64 + swz], &As[r * 64]);
            gload16(&WallT[(size_t)(tn * 128 + r + srow) * C_ + kt * 64 + swz], &Bs[r * 64]);
        }
        asm volatile("s_waitcnt vmcnt(0)" ::: "memory");
        __syncthreads();
        for (int ks = 0; ks < 2; ++ks) {
            bf16x8 aF[4], bF[4];
            for (int mi = 0; mi < 4; mi++)
                aF[mi] = *(const bf16x8*)&As[rc(wm * 64 + mi * 16 + l15, ks * 4 + l4)];
            for (int ni = 0; ni < 4; ni++)
                bF[ni] = *(const bf16x8*)&Bs[rc(wn * 64 + ni * 16 + l15, ks * 4 + l4)];
            for (int mi = 0; mi < 4; mi++)
                for (int ni = 0; ni < 4; ni++)
                    acc[mi][ni] = __builtin_amdgcn_mfma_f32_16x16x32_bf16(
                        aF[mi], bF[ni], acc[mi][ni], 0, 0, 0);
        }
    }
    for (int mi = 0; mi < 4; mi++)
        for (int ni = 0; ni < 4; ni++)
            for (int j = 0; j < 4; j++) {
                int row = tm * 128 + wm * 64 + mi * 16 + l4 * 4 + j;
                int col = tn * 128 + wn * 64 + ni * 16 + l15;
                P[(size_t)row * NW + col] = f2bf(acc[mi][ni][j] + bias[col]);
            }
}

// ---------------- V transpose via LDS tile: Vt[bh][d][s]
__global__ __launch_bounds__(256) void vt_kernel(
    const u16* __restrict__ P, u16* __restrict__ Vt)
{
    __shared__ u16 T[64][72];
    int st = blockIdx.x, bh = blockIdx.y;
    int b = bh / H_, h = bh % H_;
    int tid = threadIdx.x;
    for (int p = 0; p < 2; p++) {
        int row = p * 32 + (tid >> 3);
        int cd = (tid & 7) * 8;
        us8 v = *(const us8*)&P[(size_t)(b * S_ + st * 64 + row) * NW + 2 * AH + h * D_ + cd];
        *(us8*)&T[row][cd] = v;
    }
    __syncthreads();
    int d = tid & 63, sg = tid >> 6;
    for (int part = 0; part < 2; part++) {
        int sl = sg * 16 + part * 8;
        us8 o;
        for (int i = 0; i < 8; i++) o[i] = T[sl + i][d];
        *(us8*)&Vt[((size_t)bh * D_ + d) * S_ + st * 64 + sl] = o;
    }
}

// ---------------- flash attention (swizzled LDS, packed P, defer-max)
__global__ __launch_bounds__(256) void flash_kernel(
    const u16* __restrict__ P, const u16* __restrict__ Vt,
    const void* __restrict__ mask, const int* __restrict__ flag,
    void* __restrict__ out)
{
    __shared__ __attribute__((aligned(16))) u16 Qs[64 * 64];
    __shared__ __attribute__((aligned(16))) u16 Ks[64 * 64];
    __shared__ __attribute__((aligned(16))) u16 Vts[64 * 64];
    __shared__ __attribute__((aligned(16))) unsigned PpS[4 * 576];
    __shared__ float Ms[S_];
    const float LOG2E = 1.4426950408889634f;

    int qt = blockIdx.x, bh = blockIdx.y;
    int b = bh / H_, h = bh % H_;
    int tid = threadIdx.x, lane = tid & 63, wvid = tid >> 6;
    int l15 = lane & 15, l4 = lane >> 4;
    int srow = lane >> 3;
    int swz = (((lane & 7) ^ (lane >> 3)) & 7) * 8;
    int isf32 = *flag;
    unsigned* Pw = &PpS[wvid * 576];

    for (int j = 0; j < 8; j++)
        Ms[tid * 8 + j] = ldmix(mask, (size_t)b * S_ + tid * 8 + j, isf32);
    for (int c = 0; c < 2; c++) {
        int r = wvid * 16 + c * 8;
        gload16(&P[(size_t)(b * S_ + qt * 64 + r + srow) * NW + h * D_ + swz], &Qs[r * 64]);
    }
    asm volatile("s_waitcnt vmcnt(0)" ::: "memory");
    __syncthreads();
    bf16x8 qf[2];
    for (int ks = 0; ks < 2; ks++)
        qf[ks] = *(const bf16x8*)&Qs[rc(wvid * 16 + l15, ks * 4 + l4)];

    f32x4 oacc[4] = {};
    float mrun = -INFINITY, lrun = 0.f;

    for (int kt = 0; kt < 32; ++kt) {
        __syncthreads();
        for (int c = 0; c < 2; c++) {
            int r = wvid * 16 + c * 8;
            gload16(&P[(size_t)(b * S_ + kt * 64 + r + srow) * NW + AH + h * D_ + swz], &Ks[r * 64]);
            gload16(&Vt[((size_t)bh * D_ + r + srow) * S_ + kt * 64 + swz], &Vts[r * 64]);
        }
        asm volatile("s_waitcnt vmcnt(0)" ::: "memory");
        __syncthreads();

        f32x4 sacc[4] = {};
        for (int ks = 0; ks < 2; ks++)
            for (int kf = 0; kf < 4; kf++) {
                bf16x8 aK = *(const bf16x8*)&Ks[rc(kf * 16 + l15, ks * 4 + l4)];
                sacc[kf] = __builtin_amdgcn_mfma_f32_16x16x32_bf16(aK, qf[ks], sacc[kf], 0, 0, 0);
            }

        float vals[4][4];
        float tmax = -INFINITY;
        for (int kf = 0; kf < 4; kf++)
            for (int j = 0; j < 4; j++) {
                float v = fmaf(sacc[kf][j], 0.125f, Ms[kt * 64 + kf * 16 + l4 * 4 + j]);
                vals[kf][j] = v;
                tmax = fmaxf(tmax, v);
            }
        tmax = fmaxf(tmax, __shfl_xor(tmax, 16));
        tmax = fmaxf(tmax, __shfl_xor(tmax, 32));
        if (!__all(tmax - mrun <= 8.0f)) {
            float mnew = fmaxf(mrun, tmax);
            float alpha = exp2f((mrun - mnew) * LOG2E);
            lrun *= alpha;
            for (int mf = 0; mf < 4; mf++) oacc[mf] *= alpha;
            mrun = mnew;
        }
        float ps = 0.f;
        for (int kf = 0; kf < 4; kf++) {
            float p0 = exp2f((vals[kf][0] - mrun) * LOG2E);
            float p1 = exp2f((vals[kf][1] - mrun) * LOG2E);
            float p2 = exp2f((vals[kf][2] - mrun) * LOG2E);
            float p3 = exp2f((vals[kf][3] - mrun) * LOG2E);
            ps += (p0 + p1) + (p2 + p3);
            union { float f; unsigned u; } b0{p0}, b1{p1}, b2{p2}, b3{p3};
            unsigned w0 = (b0.u >> 16) | (b1.u & 0xffff0000u);
            unsigned w1 = (b2.u >> 16) | (b3.u & 0xffff0000u);
            unsigned idx = l15 * 36 + kf * 8 + l4 * 2;
            Pw[idx] = w0;
            Pw[idx + 1] = w1;
        }
        ps += __shfl_xor(ps, 16);
        ps += __shfl_xor(ps, 32);
        lrun += ps;
        asm volatile("s_waitcnt lgkmcnt(0)" ::: "memory");
        __builtin_amdgcn_sched_barrier(0);

        for (int ks2 = 0; ks2 < 2; ks2++) {
            bf16x8 pf = *(const bf16x8*)&Pw[l15 * 36 + ks2 * 16 + l4 * 4];
            for (int mf = 0; mf < 4; mf++) {
                bf16x8 av = *(const bf16x8*)&Vts[rc(mf * 16 + l15, ks2 * 4 + l4)];
                oacc[mf] = __builtin_amdgcn_mfma_f32_16x16x32_bf16(av, pf, oacc[mf], 0, 0, 0);
            }
        }
    }
    float rinv = 1.0f / lrun;
    int tok = qt * 64 + wvid * 16 + l15;
    for (int mf = 0; mf < 4; mf++)
        for (int j = 0; j < 4; j++) {
            int d = mf * 16 + l4 * 4 + j;
            size_t oi = (size_t)(b * S_ + tok) * C_ + h * D_ + d;
            float val = oacc[mf][j] * rinv;
            if (isf32) ((float*)out)[oi] = val; else ((u16*)out)[oi] = f2bf(val);
        }
}

// ---------------- dynamic-kernel logits: L[8192][64] = (q .* key_conv) @ WckT^T + bck  (MFMA)
__global__ __launch_bounds__(256) void dynlogit_kernel(
    const u16* __restrict__ P, const u16* __restrict__ WckT,
    const float* __restrict__ bckc, float* __restrict__ L)
{
    __shared__ __attribute__((aligned(16))) u16 As[64 * 64];
    __shared__ __attribute__((aligned(16))) u16 Bs[64 * 64];
    int tok0 = blockIdx.x * 64;
    int tid = threadIdx.x;
    int lane = tid & 63, w = tid >> 6;
    int l15 = lane & 15, l4 = lane >> 4;
    int srow = lane >> 3;
    int swz = (((lane & 7) ^ (lane >> 3)) & 7) * 8;
    int ar = tid >> 2;             // A-stage row (64 rows, 4 threads/row)
    int ac0 = (tid & 3) * 16;      // A-stage col base (16 cols = 2 chunks)
    f32x4 acc[4] = {};
    for (int kt = 0; kt < 6; ++kt) {
        __syncthreads();
        // stage B = WckT[64][AH] chunk via global_load_lds (pre-swizzled source, K-stride AH)
        for (int c = 0; c < 2; c++) {
            int r = w * 16 + c * 8;
            gload16(&WckT[(size_t)(r + srow) * AH + kt * 64 + swz], &Bs[r * 64]);
        }
        // stage A = (q .* kc) chunk, computed in registers, swizzled ds_write
        {
            size_t base = (size_t)(tok0 + ar) * NW + kt * 64 + ac0;
            us8 qv0 = *(const us8*)&P[base];
            us8 qv1 = *(const us8*)&P[base + 8];
            us8 kv0 = *(const us8*)&P[base + 4 * AH];
            us8 kv1 = *(const us8*)&P[base + 4 * AH + 8];
            us8 o0, o1;
            for (int i = 0; i < 8; i++) {
                o0[i] = f2bf(bf2f(qv0[i]) * bf2f(kv0[i]));
                o1[i] = f2bf(bf2f(qv1[i]) * bf2f(kv1[i]));
            }
            int cb = ac0 >> 3;
            *(us8*)&As[rc(ar, cb)] = o0;
            *(us8*)&As[rc(ar, cb + 1)] = o1;
        }
        asm volatile("s_waitcnt vmcnt(0)" ::: "memory");
        __syncthreads();
        for (int ks = 0; ks < 2; ++ks) {
            bf16x8 aF = *(const bf16x8*)&As[rc(w * 16 + l15, ks * 4 + l4)];
            for (int ni = 0; ni < 4; ni++) {
                bf16x8 bF = *(const bf16x8*)&Bs[rc(ni * 16 + l15, ks * 4 + l4)];
                acc[ni] = __builtin_amdgcn_mfma_f32_16x16x32_bf16(aF, bF, acc[ni], 0, 0, 0);
            }
        }
    }
    for (int j = 0; j < 4; j++) {
        int tok = tok0 + w * 16 + l4 * 4 + j;
        for (int ni = 0; ni < 4; ni++) {
            int col = ni * 16 + l15;
            if (col < NCK) L[(size_t)tok * 64 + col] = acc[ni][j] + bckc[col];
        }
    }
}

// ---------------- dynamic conv context: softmax(9) + window MAC, thread per 8 channels
__global__ __launch_bounds__(256) void dynctx_kernel(
    const u16* __restrict__ P, const float* __restrict__ L,
    const int* __restrict__ flag, void* __restrict__ out)
{
    const float LOG2E = 1.4426950408889634f;
    int idx = blockIdx.x * 256 + threadIdx.x;   // 8192 * 48 = 393216 threads
    int g = idx % 48, tok = idx / 48;
    int ch0 = g * 8, h = ch0 >> 6;
    int s = tok & (S_ - 1);
    int isf32 = *flag;
    float lg[KK];
    float m = -INFINITY;
    for (int k = 0; k < KK; k++) {
        lg[k] = L[(size_t)tok * 64 + h * KK + k];
        m = fmaxf(m, lg[k]);
    }
    float ssum = 0.f;
    for (int k = 0; k < KK; k++) {
        lg[k] = exp2f((lg[k] - m) * LOG2E);
        ssum += lg[k];
    }
    float sinv = 1.0f / ssum;
    float acc[8];
    for (int i = 0; i < 8; i++) acc[i] = 0.f;
    for (int k = 0; k < KK; k++) {
        int ss = s + k - 4;
        if (ss < 0 || ss >= S_) continue;
        us8 v = *(const us8*)&P[(size_t)(tok + k - 4) * NW + 3 * AH + ch0];
        float kw = lg[k] * sinv;
        for (int i = 0; i < 8; i++) acc[i] = fmaf(kw, bf2f(v[i]), acc[i]);
    }
    size_t oi = (size_t)tok * C_ + AH + ch0;
    if (isf32) {
        float4v o0, o1;
        for (int i = 0; i < 4; i++) { o0[i] = acc[i]; o1[i] = acc[4 + i]; }
        *(float4v*)((float*)out + oi) = o0;
        *(float4v*)((float*)out + oi + 4) = o1;
    } else {
        us8 o;
        for (int i = 0; i < 8; i++) o[i] = f2bf(acc[i]);
        *(us8*)((u16*)out + oi) = o;
    }
}

extern "C" void kernel_launch(void* const* d_in, const int* in_sizes, int n_in,
                              void* d_out, int out_size, void* d_ws, size_t ws_size,
                              hipStream_t stream) {
    const void* hidden = d_in[0];
    const void* mask   = d_in[1];
    const void* Wq  = d_in[2];
    const void* bq  = d_in[3];
    const void* Wk  = d_in[4];
    const void* bk  = d_in[5];
    const void* Wv  = d_in[6];
    const void* bv  = d_in[7];
    const void* dwk = d_in[8];
    const void* pw  = d_in[9];
    const void* cb  = d_in[10];
    const void* Wck = d_in[11];
    const void* bck = d_in[12];
    const void* Wco = d_in[13];
    const void* bco = d_in[14];
    char* ws = (char*)d_ws;

    const size_t NEED = 65934608u;
    if (ws_size < NEED) return;

    u16*   Pbuf  = (u16*)(ws);                       // 31,457,280
    u16*   Hbf   = (u16*)(ws + 31457280);            // 12,582,912 (L aliases this after gemm)
    u16*   dwb   = (u16*)(ws + 44040192);            // 12,582,912
    u16*   WallT = (u16*)(ws + 56623104);            //  2,949,120
    float* bias  = (float*)(ws + 59572224);          //      7,680
    u16*   Vt    = (u16*)(ws + 59579904);            //  6,291,456
    u16*   dwkc  = (u16*)(ws + 65871360);            //     13,824
    u16*   WckT  = (u16*)(ws + 65885184);            //     49,152 = 64*AH*2
    float* bckc  = (float*)(ws + 65934336);          //        256
    int*   flag  = (int*)(ws + 65934592);            //         16
    float* Lbuf  = (float*)Hbf;                      //  2,097,152 (alias)

    sniff_kernel<<<1, 1024, 0, stream>>>((const unsigned*)hidden, flag);
    canon_kernel<<<124, 256, 0, stream>>>(dwk, Wck, bck, flag, dwkc, WckT, bckc);
    prep_kernel<<<720, 256, 0, stream>>>(Wq, Wk, Wv, Wco, pw, bq, bk, bv, bco, cb, flag, WallT, bias);
    dwconv_kernel<<<384, 256, 0, stream>>>(hidden, dwkc, flag, Hbf, dwb);
    gemm_kernel<<<960, 256, 0, stream>>>(Hbf, dwb, WallT, bias, Pbuf);
    vt_kernel<<<dim3(32, 24), 256, 0, stream>>>(Pbuf, Vt);
    dynlogit_kernel<<<128, 256, 0, stream>>>(Pbuf, WckT, bckc, Lbuf);
    flash_kernel<<<dim3(32, 24), 256, 0, stream>>>(Pbuf, Vt, mask, flag, d_out);
    dynctx_kernel<<<1536, 256, 0, stream>>>(Pbuf, Lbuf, flag, d_out);
}

// Round 10
// 251.835 us; speedup vs baseline: 1.3988x; 1.0162x over previous
//
#include <hip/hip_runtime.h>

#define B_    4
#define S_    2048
#define C_    768
#define AH    384
#define H_    6
#define D_    64
#define KK    9
#define NTOK  (B_*S_)
#define NW    1920   // q | k | v | conv_out | key_conv
#define NCK   (H_*KK)   // 54

typedef unsigned short u16;
typedef __attribute__((ext_vector_type(8))) short   bf16x8;
typedef __attribute__((ext_vector_type(4))) float   f32x4;
typedef __attribute__((ext_vector_type(4))) float   float4v;
typedef __attribute__((ext_vector_type(8))) unsigned short us8;

__device__ __forceinline__ float bf2f(u16 u) {
    union { unsigned u; float f; } x; x.u = ((unsigned)u) << 16; return x.f;
}
__device__ __forceinline__ u16 f2bf(float f) {
    union { float f; unsigned u; } x; x.f = f;
    unsigned r = x.u + 0x7fff + ((x.u >> 16) & 1);
    return (u16)(r >> 16);
}
__device__ __forceinline__ float ldmix(const void* p, size_t i, int isf32) {
    return isf32 ? ((const float*)p)[i] : bf2f(((const u16*)p)[i]);
}
__device__ __forceinline__ void gload16(const u16* g, u16* l) {
    __builtin_amdgcn_global_load_lds(
        (const __attribute__((address_space(1))) unsigned int*)g,
        (__attribute__((address_space(3))) unsigned int*)l, 16, 0, 0);
}
// swizzled-read index into a [rows][64 u16] LDS tile staged with pre-swizzled source:
// logical (row, 16B-chunk cb) lives at chunk cb ^ (row&7)
__device__ __forceinline__ int rc(int row, int cb) {
    return row * 64 + (((cb) ^ (row & 7)) << 3);
}

// ---------------- dtype sniff: flag=1 if inputs are fp32, 0 if bf16
__global__ __launch_bounds__(1024) void sniff_kernel(const unsigned* __restrict__ h,
                                                     int* __restrict__ flag)
{
    __shared__ int cnt;
    if (threadIdx.x == 0) cnt = 0;
    __syncthreads();
    unsigned u = h[threadIdx.x];
    int e = (u >> 7) & 0xFF;
    if (e >= 120 && e <= 134) atomicAdd(&cnt, 1);
    __syncthreads();
    if (threadIdx.x == 0) *flag = (cnt < 512) ? 1 : 0;
}

// ---------------- canonicalize small tensors: dwkc (bf16), WckT[64][AH] (bf16, padded), bckc (f32)
__global__ __launch_bounds__(256) void canon_kernel(
    const void* __restrict__ dwk, const void* __restrict__ Wck,
    const void* __restrict__ bck, const int* __restrict__ flag,
    u16* __restrict__ dwkc, u16* __restrict__ WckT, float* __restrict__ bckc)
{
    int t = blockIdx.x * 256 + threadIdx.x;
    int isf32 = *flag;
    if (t < C_ * KK) { dwkc[t] = f2bf(ldmix(dwk, t, isf32)); return; }
    int u = t - C_ * KK;
    if (u < 64 * AH) {   // WckT[o][c] = Wck[c][o], zero-padded rows 54..63; K-stride = AH
        int o = u / AH, c = u % AH;
        WckT[u] = (o < NCK) ? f2bf(ldmix(Wck, (size_t)c * NCK + o, isf32)) : (u16)0;
        return;
    }
    u -= 64 * AH;
    if (u < NCK) { bckc[u] = ldmix(bck, u, isf32); return; }
}

// ---------------- prep: WallT[1920][768] = [Wq|Wk|Wv|Wco]^T | pw ; bias_all[1920]
__global__ __launch_bounds__(256) void prep_kernel(
    const void* __restrict__ Wq, const void* __restrict__ Wk,
    const void* __restrict__ Wv, const void* __restrict__ Wco,
    const void* __restrict__ pw,
    const void* __restrict__ bq, const void* __restrict__ bk,
    const void* __restrict__ bv, const void* __restrict__ bco,
    const void* __restrict__ cb, const int* __restrict__ flag,
    u16* __restrict__ WallT, float* __restrict__ bias)
{
    int t = blockIdx.x * 256 + threadIdx.x;
    if (t >= NW * 96) return;
    int isf32 = *flag;
    int n = t / 96, k8 = t % 96;
    int g = n / AH, m = n % AH;
    us8 v;
    if (g < 4) {
        const void* W = (g == 0) ? Wq : (g == 1) ? Wk : (g == 2) ? Wv : Wco;
        for (int i = 0; i < 8; i++) v[i] = f2bf(ldmix(W, (size_t)(k8 * 8 + i) * AH + m, isf32));
    } else {
        for (int i = 0; i < 8; i++) v[i] = f2bf(ldmix(pw, (size_t)m * C_ + k8 * 8 + i, isf32));
    }
    *(us8*)&WallT[(size_t)n * C_ + k8 * 8] = v;
    if (k8 == 0) {
        const void* bs = (g == 0) ? bq : (g == 1) ? bk : (g == 2) ? bv : (g == 3) ? bco : cb;
        bias[n] = ldmix(bs, m, isf32);
    }
}

// ---------------- depthwise conv + Hbf production (reads raw hidden)
__global__ __launch_bounds__(256) void dwconv_kernel(
    const void* __restrict__ x, const u16* __restrict__ dwkc,
    const int* __restrict__ flag, u16* __restrict__ Hbf, u16* __restrict__ dwout)
{
    int t = blockIdx.x * 256 + threadIdx.x;   // 98304 threads
    int isf32 = *flag;
    int cg = t % 96, u = t / 96;
    int b = u >> 8, s0 = (u & 255) << 3;
    int c0 = cg * 8;
    float wf[KK][8];
    for (int k = 0; k < KK; k++)
        for (int i = 0; i < 8; i++) wf[k][i] = bf2f(dwkc[(c0 + i) * KK + k]);
    float acc[8][8];
    for (int s = 0; s < 8; s++) for (int i = 0; i < 8; i++) acc[s][i] = 0.f;
    for (int r = 0; r < 16; r++) {
        int ss = s0 + r - 4;
        if (ss < 0 || ss >= S_) continue;
        float xf[8];
        size_t base = ((size_t)(b * S_ + ss)) * C_ + c0;
        if (isf32) {
            float4v v0 = *(const float4v*)((const float*)x + base);
            float4v v1 = *(const float4v*)((const float*)x + base + 4);
            for (int i = 0; i < 4; i++) { xf[i] = v0[i]; xf[4 + i] = v1[i]; }
        } else {
            us8 xv = *(const us8*)((const u16*)x + base);
            for (int i = 0; i < 8; i++) xf[i] = bf2f(xv[i]);
        }
        if (r >= 4 && r < 12) {
            us8 o;
            for (int i = 0; i < 8; i++) o[i] = f2bf(xf[i]);
            *(us8*)&Hbf[base] = o;
        }
        for (int k = 0; k < KK; k++) {
            int so = r - k;
            if (so < 0 || so >= 8) continue;
            for (int i = 0; i < 8; i++) acc[so][i] += xf[i] * wf[k][i];
        }
    }
    for (int s = 0; s < 8; s++) {
        us8 o;
        for (int i = 0; i < 8; i++) o[i] = f2bf(acc[s][i]);
        *(us8*)&dwout[((size_t)(b * S_ + s0 + s)) * C_ + c0] = o;
    }
}

// ---------------- big GEMM: P[8192][1920] = A * WallT^T + bias  (swizzled LDS)
__global__ __launch_bounds__(256) void gemm_kernel(
    const u16* __restrict__ hidden, const u16* __restrict__ dwb,
    const u16* __restrict__ WallT, const float* __restrict__ bias,
    u16* __restrict__ P)
{
    __shared__ __attribute__((aligned(16))) u16 As[128 * 64];
    __shared__ __attribute__((aligned(16))) u16 Bs[128 * 64];
    int bx = blockIdx.x;
    int tm = bx % 64, tn = bx / 64;
    const u16* A = (tn >= 12) ? dwb : hidden;
    int tid = threadIdx.x;
    int lane = tid & 63, wv = tid >> 6;
    int wm = wv >> 1, wn = wv & 1;
    int l15 = lane & 15, l4 = lane >> 4;
    int srow = lane >> 3;
    int swz = (((lane & 7) ^ (lane >> 3)) & 7) * 8;
    f32x4 acc[4][4] = {};
    for (int kt = 0; kt < 12; ++kt) {
        __syncthreads();
        for (int c = 0; c < 4; c++) {
            int r = wv * 32 + c * 8;
            gload16(&A[(size_t)(tm * 128 + r + srow) * C_ + kt * 64 + swz], &As[r * 64]);
            gload16(&WallT[(size_t)(tn * 128 + r + srow) * C_ + kt * 64 + swz], &Bs[r * 64]);
        }
        asm volatile("s_waitcnt vmcnt(0)" ::: "memory");
        __syncthreads();
        for (int ks = 0; ks < 2; ++ks) {
            bf16x8 aF[4], bF[4];
            for (int mi = 0; mi < 4; mi++)
                aF[mi] = *(const bf16x8*)&As[rc(wm * 64 + mi * 16 + l15, ks * 4 + l4)];
            for (int ni = 0; ni < 4; ni++)
                bF[ni] = *(const bf16x8*)&Bs[rc(wn * 64 + ni * 16 + l15, ks * 4 + l4)];
            for (int mi = 0; mi < 4; mi++)
                for (int ni = 0; ni < 4; ni++)
                    acc[mi][ni] = __builtin_amdgcn_mfma_f32_16x16x32_bf16(
                        aF[mi], bF[ni], acc[mi][ni], 0, 0, 0);
        }
    }
    for (int mi = 0; mi < 4; mi++)
        for (int ni = 0; ni < 4; ni++)
            for (int j = 0; j < 4; j++) {
                int row = tm * 128 + wm * 64 + mi * 16 + l4 * 4 + j;
                int col = tn * 128 + wn * 64 + ni * 16 + l15;
                P[(size_t)row * NW + col] = f2bf(acc[mi][ni][j] + bias[col]);
            }
}

// ---------------- V transpose via LDS tile: Vt[bh][d][s]
__global__ __launch_bounds__(256) void vt_kernel(
    const u16* __restrict__ P, u16* __restrict__ Vt)
{
    __shared__ u16 T[64][72];
    int st = blockIdx.x, bh = blockIdx.y;
    int b = bh / H_, h = bh % H_;
    int tid = threadIdx.x;
    for (int p = 0; p < 2; p++) {
        int row = p * 32 + (tid >> 3);
        int cd = (tid & 7) * 8;
        us8 v = *(const us8*)&P[(size_t)(b * S_ + st * 64 + row) * NW + 2 * AH + h * D_ + cd];
        *(us8*)&T[row][cd] = v;
    }
    __syncthreads();
    int d = tid & 63, sg = tid >> 6;
    for (int part = 0; part < 2; part++) {
        int sl = sg * 16 + part * 8;
        us8 o;
        for (int i = 0; i < 8; i++) o[i] = T[sl + i][d];
        *(us8*)&Vt[((size_t)bh * D_ + d) * S_ + st * 64 + sl] = o;
    }
}

// ---------------- flash attention: 2-phase prefetch pipeline, double-buffered K/V,
//                  swizzled LDS, packed P (overlaid on dead Q region), bf16 mask, defer-max
__global__ __launch_bounds__(256) void flash_kernel(
    const u16* __restrict__ P, const u16* __restrict__ Vt,
    const void* __restrict__ mask, const int* __restrict__ flag,
    void* __restrict__ out)
{
    // LDS map (bytes): [0,9216) PpS (overlays Qs [0,8192), Q dead after prologue)
    //                  [9216,25600) Ks dbuf | [25600,41984) Vts dbuf | [41984,46080) Ms bf16
    __shared__ __attribute__((aligned(16))) u16 lds[23040];   // 46080 B -> 3 blocks/CU
    const float LOG2E = 1.4426950408889634f;

    int qt = blockIdx.x, bh = blockIdx.y;
    int b = bh / H_, h = bh % H_;
    int tid = threadIdx.x, lane = tid & 63, wvid = tid >> 6;
    int l15 = lane & 15, l4 = lane >> 4;
    int srow = lane >> 3;
    int swz = (((lane & 7) ^ (lane >> 3)) & 7) * 8;
    int isf32 = *flag;
    u16* Qs  = lds;                       // prologue only
    u16* MsB = lds + 20992;               // 2048 bf16
    unsigned* Pw = (unsigned*)lds + wvid * 576;

    {   // stage mask as bf16
        us8 mv;
        for (int j = 0; j < 8; j++) mv[j] = f2bf(ldmix(mask, (size_t)b * S_ + tid * 8 + j, isf32));
        *(us8*)&MsB[tid * 8] = mv;
    }
    for (int c = 0; c < 2; c++) {         // stage Q tile [64 q][64 d]
        int r = wvid * 16 + c * 8;
        gload16(&P[(size_t)(b * S_ + qt * 64 + r + srow) * NW + h * D_ + swz], &Qs[r * 64]);
    }
    {   // stage K/V tile 0 into buffer 0
        for (int c = 0; c < 2; c++) {
            int r = wvid * 16 + c * 8;
            gload16(&P[(size_t)(b * S_ + 0 * 64 + r + srow) * NW + AH + h * D_ + swz],
                    &lds[4608 + r * 64]);
            gload16(&Vt[((size_t)bh * D_ + r + srow) * S_ + 0 * 64 + swz],
                    &lds[12800 + r * 64]);
        }
    }
    asm volatile("s_waitcnt vmcnt(0)" ::: "memory");
    __syncthreads();
    bf16x8 qf[2];
    for (int ks = 0; ks < 2; ks++)
        qf[ks] = *(const bf16x8*)&Qs[rc(wvid * 16 + l15, ks * 4 + l4)];
    __syncthreads();   // all qf reads done before any PpS write (PpS overlays Qs)

    f32x4 oacc[4] = {};
    float mrun = -INFINITY, lrun = 0.f;
    int cur = 0;

    for (int kt = 0; kt < 32; ++kt) {
        // issue next tile's staging into the other buffer (latency hides under compute)
        if (kt < 31) {
            u16* Ksd = lds + 4608 + ((cur ^ 1) << 12);
            u16* Vsd = lds + 12800 + ((cur ^ 1) << 12);
            for (int c = 0; c < 2; c++) {
                int r = wvid * 16 + c * 8;
                gload16(&P[(size_t)(b * S_ + (kt + 1) * 64 + r + srow) * NW + AH + h * D_ + swz],
                        &Ksd[r * 64]);
                gload16(&Vt[((size_t)bh * D_ + r + srow) * S_ + (kt + 1) * 64 + swz],
                        &Vsd[r * 64]);
            }
        }
        const u16* Ksr = lds + 4608 + (cur << 12);
        const u16* Vsr = lds + 12800 + (cur << 12);

        // S^T = K * Q^T : lane holds S[key = kf*16 + l4*4 + j][q = l15]
        f32x4 sacc[4] = {};
        for (int ks = 0; ks < 2; ks++)
            for (int kf = 0; kf < 4; kf++) {
                bf16x8 aK = *(const bf16x8*)&Ksr[rc(kf * 16 + l15, ks * 4 + l4)];
                sacc[kf] = __builtin_amdgcn_mfma_f32_16x16x32_bf16(aK, qf[ks], sacc[kf], 0, 0, 0);
            }

        float vals[4][4];
        float tmax = -INFINITY;
        for (int kf = 0; kf < 4; kf++)
            for (int j = 0; j < 4; j++) {
                float v = fmaf(sacc[kf][j], 0.125f, bf2f(MsB[kt * 64 + kf * 16 + l4 * 4 + j]));
                vals[kf][j] = v;
                tmax = fmaxf(tmax, v);
            }
        tmax = fmaxf(tmax, __shfl_xor(tmax, 16));
        tmax = fmaxf(tmax, __shfl_xor(tmax, 32));
        if (!__all(tmax - mrun <= 8.0f)) {      // defer-max (THR=8)
            float mnew = fmaxf(mrun, tmax);
            float alpha = exp2f((mrun - mnew) * LOG2E);
            lrun *= alpha;
            for (int mf = 0; mf < 4; mf++) oacc[mf] *= alpha;
            mrun = mnew;
        }
        float ps = 0.f;
        for (int kf = 0; kf < 4; kf++) {
            float p0 = exp2f((vals[kf][0] - mrun) * LOG2E);
            float p1 = exp2f((vals[kf][1] - mrun) * LOG2E);
            float p2 = exp2f((vals[kf][2] - mrun) * LOG2E);
            float p3 = exp2f((vals[kf][3] - mrun) * LOG2E);
            ps += (p0 + p1) + (p2 + p3);
            union { float f; unsigned u; } b0{p0}, b1{p1}, b2{p2}, b3{p3};
            unsigned w0 = (b0.u >> 16) | (b1.u & 0xffff0000u);
            unsigned w1 = (b2.u >> 16) | (b3.u & 0xffff0000u);
            unsigned idx = l15 * 36 + kf * 8 + l4 * 2;
            Pw[idx] = w0;
            Pw[idx + 1] = w1;
        }
        ps += __shfl_xor(ps, 16);
        ps += __shfl_xor(ps, 32);
        lrun += ps;
        asm volatile("s_waitcnt lgkmcnt(0)" ::: "memory");
        __builtin_amdgcn_sched_barrier(0);

        // O^T += V^T * P^T : lane holds O[d = mf*16 + l4*4 + j][q = l15]
        for (int ks2 = 0; ks2 < 2; ks2++) {
            bf16x8 pf = *(const bf16x8*)&Pw[l15 * 36 + ks2 * 16 + l4 * 4];
            for (int mf = 0; mf < 4; mf++) {
                bf16x8 av = *(const bf16x8*)&Vsr[rc(mf * 16 + l15, ks2 * 4 + l4)];
                oacc[mf] = __builtin_amdgcn_mfma_f32_16x16x32_bf16(av, pf, oacc[mf], 0, 0, 0);
            }
        }
        // next tile's staging landed + all waves done reading buf[cur] before it's overwritten
        asm volatile("s_waitcnt vmcnt(0)" ::: "memory");
        __syncthreads();
        cur ^= 1;
    }
    float rinv = 1.0f / lrun;
    int tok = qt * 64 + wvid * 16 + l15;
    for (int mf = 0; mf < 4; mf++)
        for (int j = 0; j < 4; j++) {
            int d = mf * 16 + l4 * 4 + j;
            size_t oi = (size_t)(b * S_ + tok) * C_ + h * D_ + d;
            float val = oacc[mf][j] * rinv;
            if (isf32) ((float*)out)[oi] = val; else ((u16*)out)[oi] = f2bf(val);
        }
}

// ---------------- dynamic-kernel logits: L[8192][64] = (q .* key_conv) @ WckT^T + bck  (MFMA)
__global__ __launch_bounds__(256) void dynlogit_kernel(
    const u16* __restrict__ P, const u16* __restrict__ WckT,
    const float* __restrict__ bckc, float* __restrict__ L)
{
    __shared__ __attribute__((aligned(16))) u16 As[64 * 64];
    __shared__ __attribute__((aligned(16))) u16 Bs[64 * 64];
    int tok0 = blockIdx.x * 64;
    int tid = threadIdx.x;
    int lane = tid & 63, w = tid >> 6;
    int l15 = lane & 15, l4 = lane >> 4;
    int srow = lane >> 3;
    int swz = (((lane & 7) ^ (lane >> 3)) & 7) * 8;
    int ar = tid >> 2;             // A-stage row (64 rows, 4 threads/row)
    int ac0 = (tid & 3) * 16;      // A-stage col base (16 cols = 2 chunks)
    f32x4 acc[4] = {};
    for (int kt = 0; kt < 6; ++kt) {
        __syncthreads();
        // stage B = WckT[64][AH] chunk via global_load_lds (pre-swizzled source, K-stride AH)
        for (int c = 0; c < 2; c++) {
            int r = w * 16 + c * 8;
            gload16(&WckT[(size_t)(r + srow) * AH + kt * 64 + swz], &Bs[r * 64]);
        }
        // stage A = (q .* kc) chunk, computed in registers, swizzled ds_write
        {
            size_t base = (size_t)(tok0 + ar) * NW + kt * 64 + ac0;
            us8 qv0 = *(const us8*)&P[base];
            us8 qv1 = *(const us8*)&P[base + 8];
            us8 kv0 = *(const us8*)&P[base + 4 * AH];
            us8 kv1 = *(const us8*)&P[base + 4 * AH + 8];
            us8 o0, o1;
            for (int i = 0; i < 8; i++) {
                o0[i] = f2bf(bf2f(qv0[i]) * bf2f(kv0[i]));
                o1[i] = f2bf(bf2f(qv1[i]) * bf2f(kv1[i]));
            }
            int cb = ac0 >> 3;
            *(us8*)&As[rc(ar, cb)] = o0;
            *(us8*)&As[rc(ar, cb + 1)] = o1;
        }
        asm volatile("s_waitcnt vmcnt(0)" ::: "memory");
        __syncthreads();
        for (int ks = 0; ks < 2; ++ks) {
            bf16x8 aF = *(const bf16x8*)&As[rc(w * 16 + l15, ks * 4 + l4)];
            for (int ni = 0; ni < 4; ni++) {
                bf16x8 bF = *(const bf16x8*)&Bs[rc(ni * 16 + l15, ks * 4 + l4)];
                acc[ni] = __builtin_amdgcn_mfma_f32_16x16x32_bf16(aF, bF, acc[ni], 0, 0, 0);
            }
        }
    }
    for (int j = 0; j < 4; j++) {
        int tok = tok0 + w * 16 + l4 * 4 + j;
        for (int ni = 0; ni < 4; ni++) {
            int col = ni * 16 + l15;
            if (col < NCK) L[(size_t)tok * 64 + col] = acc[ni][j] + bckc[col];
        }
    }
}

// ---------------- dynamic conv context: softmax(9) + window MAC, thread per 8 channels
__global__ __launch_bounds__(256) void dynctx_kernel(
    const u16* __restrict__ P, const float* __restrict__ L,
    const int* __restrict__ flag, void* __restrict__ out)
{
    const float LOG2E = 1.4426950408889634f;
    int idx = blockIdx.x * 256 + threadIdx.x;   // 8192 * 48 = 393216 threads
    int g = idx % 48, tok = idx / 48;
    int ch0 = g * 8, h = ch0 >> 6;
    int s = tok & (S_ - 1);
    int isf32 = *flag;
    float lg[KK];
    float m = -INFINITY;
    for (int k = 0; k < KK; k++) {
        lg[k] = L[(size_t)tok * 64 + h * KK + k];
        m = fmaxf(m, lg[k]);
    }
    float ssum = 0.f;
    for (int k = 0; k < KK; k++) {
        lg[k] = exp2f((lg[k] - m) * LOG2E);
        ssum += lg[k];
    }
    float sinv = 1.0f / ssum;
    float acc[8];
    for (int i = 0; i < 8; i++) acc[i] = 0.f;
    for (int k = 0; k < KK; k++) {
        int ss = s + k - 4;
        if (ss < 0 || ss >= S_) continue;
        us8 v = *(const us8*)&P[(size_t)(tok + k - 4) * NW + 3 * AH + ch0];
        float kw = lg[k] * sinv;
        for (int i = 0; i < 8; i++) acc[i] = fmaf(kw, bf2f(v[i]), acc[i]);
    }
    size_t oi = (size_t)tok * C_ + AH + ch0;
    if (isf32) {
        float4v o0, o1;
        for (int i = 0; i < 4; i++) { o0[i] = acc[i]; o1[i] = acc[4 + i]; }
        *(float4v*)((float*)out + oi) = o0;
        *(float4v*)((float*)out + oi + 4) = o1;
    } else {
        us8 o;
        for (int i = 0; i < 8; i++) o[i] = f2bf(acc[i]);
        *(us8*)((u16*)out + oi) = o;
    }
}

extern "C" void kernel_launch(void* const* d_in, const int* in_sizes, int n_in,
                              void* d_out, int out_size, void* d_ws, size_t ws_size,
                              hipStream_t stream) {
    const void* hidden = d_in[0];
    const void* mask   = d_in[1];
    const void* Wq  = d_in[2];
    const void* bq  = d_in[3];
    const void* Wk  = d_in[4];
    const void* bk  = d_in[5];
    const void* Wv  = d_in[6];
    const void* bv  = d_in[7];
    const void* dwk = d_in[8];
    const void* pw  = d_in[9];
    const void* cb  = d_in[10];
    const void* Wck = d_in[11];
    const void* bck = d_in[12];
    const void* Wco = d_in[13];
    const void* bco = d_in[14];
    char* ws = (char*)d_ws;

    const size_t NEED = 65934608u;
    if (ws_size < NEED) return;

    u16*   Pbuf  = (u16*)(ws);                       // 31,457,280
    u16*   Hbf   = (u16*)(ws + 31457280);            // 12,582,912 (L aliases this after gemm)
    u16*   dwb   = (u16*)(ws + 44040192);            // 12,582,912
    u16*   WallT = (u16*)(ws + 56623104);            //  2,949,120
    float* bias  = (float*)(ws + 59572224);          //      7,680
    u16*   Vt    = (u16*)(ws + 59579904);            //  6,291,456
    u16*   dwkc  = (u16*)(ws + 65871360);            //     13,824
    u16*   WckT  = (u16*)(ws + 65885184);            //     49,152 = 64*AH*2
    float* bckc  = (float*)(ws + 65934336);          //        256
    int*   flag  = (int*)(ws + 65934592);            //         16
    float* Lbuf  = (float*)Hbf;                      //  2,097,152 (alias)

    sniff_kernel<<<1, 1024, 0, stream>>>((const unsigned*)hidden, flag);
    canon_kernel<<<124, 256, 0, stream>>>(dwk, Wck, bck, flag, dwkc, WckT, bckc);
    prep_kernel<<<720, 256, 0, stream>>>(Wq, Wk, Wv, Wco, pw, bq, bk, bv, bco, cb, flag, WallT, bias);
    dwconv_kernel<<<384, 256, 0, stream>>>(hidden, dwkc, flag, Hbf, dwb);
    gemm_kernel<<<960, 256, 0, stream>>>(Hbf, dwb, WallT, bias, Pbuf);
    vt_kernel<<<dim3(32, 24), 256, 0, stream>>>(Pbuf, Vt);
    dynlogit_kernel<<<128, 256, 0, stream>>>(Pbuf, WckT, bckc, Lbuf);
    flash_kernel<<<dim3(32, 24), 256, 0, stream>>>(Pbuf, Vt, mask, flag, d_out);
    dynctx_kernel<<<1536, 256, 0, stream>>>(Pbuf, Lbuf, flag, d_out);
}

// Round 11
// 242.649 us; speedup vs baseline: 1.4517x; 1.0379x over previous
//
#include <hip/hip_runtime.h>

#define B_    4
#define S_    2048
#define C_    768
#define AH    384
#define H_    6
#define D_    64
#define KK    9
#define NTOK  (B_*S_)
#define NW    1920   // q | k | v | conv_out | key_conv
#define NCK   (H_*KK)   // 54

typedef unsigned short u16;
typedef __attribute__((ext_vector_type(8))) short   bf16x8;
typedef __attribute__((ext_vector_type(4))) float   f32x4;
typedef __attribute__((ext_vector_type(4))) float   float4v;
typedef __attribute__((ext_vector_type(8))) unsigned short us8;

__device__ __forceinline__ float bf2f(u16 u) {
    union { unsigned u; float f; } x; x.u = ((unsigned)u) << 16; return x.f;
}
__device__ __forceinline__ u16 f2bf(float f) {
    union { float f; unsigned u; } x; x.f = f;
    unsigned r = x.u + 0x7fff + ((x.u >> 16) & 1);
    return (u16)(r >> 16);
}
__device__ __forceinline__ float ldmix(const void* p, size_t i, int isf32) {
    return isf32 ? ((const float*)p)[i] : bf2f(((const u16*)p)[i]);
}
__device__ __forceinline__ void gload16(const u16* g, u16* l) {
    __builtin_amdgcn_global_load_lds(
        (const __attribute__((address_space(1))) unsigned int*)g,
        (__attribute__((address_space(3))) unsigned int*)l, 16, 0, 0);
}
// swizzled-read index into a [rows][64 u16] LDS tile staged with pre-swizzled source
__device__ __forceinline__ int rc(int row, int cb) {
    return row * 64 + (((cb) ^ (row & 7)) << 3);
}
// 128-wide variant for the V^T tile [64][128]
__device__ __forceinline__ int rc128(int row, int cb) {
    return row * 128 + (((cb) ^ (row & 7)) << 3);
}

// ---------------- dtype sniff: flag[0]=1 if fp32; flag[1] pre-zeroed for mask scan
__global__ __launch_bounds__(1024) void sniff_kernel(const unsigned* __restrict__ h,
                                                     int* __restrict__ flag)
{
    __shared__ int cnt;
    if (threadIdx.x == 0) cnt = 0;
    __syncthreads();
    unsigned u = h[threadIdx.x];
    int e = (u >> 7) & 0xFF;
    if (e >= 120 && e <= 134) atomicAdd(&cnt, 1);
    __syncthreads();
    if (threadIdx.x == 0) { flag[0] = (cnt < 512) ? 1 : 0; flag[1] = 0; }
}

// ---------------- canonicalize small tensors + mask nonzero scan
__global__ __launch_bounds__(256) void canon_kernel(
    const void* __restrict__ dwk, const void* __restrict__ Wck,
    const void* __restrict__ bck, const void* __restrict__ mask,
    int* __restrict__ flag,
    u16* __restrict__ dwkc, u16* __restrict__ WckT, float* __restrict__ bckc)
{
    int t = blockIdx.x * 256 + threadIdx.x;
    int isf32 = flag[0];
    if (t < C_ * KK) { dwkc[t] = f2bf(ldmix(dwk, t, isf32)); return; }
    int u = t - C_ * KK;
    if (u < 64 * AH) {   // WckT[o][c] = Wck[c][o], zero-padded rows 54..63; K-stride = AH
        int o = u / AH, c = u % AH;
        WckT[u] = (o < NCK) ? f2bf(ldmix(Wck, (size_t)c * NCK + o, isf32)) : (u16)0;
        return;
    }
    u -= 64 * AH;
    if (u < NCK) { bckc[u] = ldmix(bck, u, isf32); return; }
    u -= NCK;
    if (u < B_ * S_) {   // mask all-zero test (mask add of -0.0 is a no-op, so !=0 is exact)
        float v = ldmix(mask, u, isf32);
        if (v != 0.0f) atomicOr((unsigned*)&flag[1], 1u);
    }
}

// ---------------- prep: WallT[1920][768] = [Wq|Wk|Wv|Wco]^T | pw ; bias_all[1920]
__global__ __launch_bounds__(256) void prep_kernel(
    const void* __restrict__ Wq, const void* __restrict__ Wk,
    const void* __restrict__ Wv, const void* __restrict__ Wco,
    const void* __restrict__ pw,
    const void* __restrict__ bq, const void* __restrict__ bk,
    const void* __restrict__ bv, const void* __restrict__ bco,
    const void* __restrict__ cb, const int* __restrict__ flag,
    u16* __restrict__ WallT, float* __restrict__ bias)
{
    int t = blockIdx.x * 256 + threadIdx.x;
    if (t >= NW * 96) return;
    int isf32 = flag[0];
    int n = t / 96, k8 = t % 96;
    int g = n / AH, m = n % AH;
    us8 v;
    if (g < 4) {
        const void* W = (g == 0) ? Wq : (g == 1) ? Wk : (g == 2) ? Wv : Wco;
        for (int i = 0; i < 8; i++) v[i] = f2bf(ldmix(W, (size_t)(k8 * 8 + i) * AH + m, isf32));
    } else {
        for (int i = 0; i < 8; i++) v[i] = f2bf(ldmix(pw, (size_t)m * C_ + k8 * 8 + i, isf32));
    }
    *(us8*)&WallT[(size_t)n * C_ + k8 * 8] = v;
    if (k8 == 0) {
        const void* bs = (g == 0) ? bq : (g == 1) ? bk : (g == 2) ? bv : (g == 3) ? bco : cb;
        bias[n] = ldmix(bs, m, isf32);
    }
}

// ---------------- depthwise conv + Hbf production (reads raw hidden)
__global__ __launch_bounds__(256) void dwconv_kernel(
    const void* __restrict__ x, const u16* __restrict__ dwkc,
    const int* __restrict__ flag, u16* __restrict__ Hbf, u16* __restrict__ dwout)
{
    int t = blockIdx.x * 256 + threadIdx.x;   // 98304 threads
    int isf32 = flag[0];
    int cg = t % 96, u = t / 96;
    int b = u >> 8, s0 = (u & 255) << 3;
    int c0 = cg * 8;
    float wf[KK][8];
    for (int k = 0; k < KK; k++)
        for (int i = 0; i < 8; i++) wf[k][i] = bf2f(dwkc[(c0 + i) * KK + k]);
    float acc[8][8];
    for (int s = 0; s < 8; s++) for (int i = 0; i < 8; i++) acc[s][i] = 0.f;
    for (int r = 0; r < 16; r++) {
        int ss = s0 + r - 4;
        if (ss < 0 || ss >= S_) continue;
        float xf[8];
        size_t base = ((size_t)(b * S_ + ss)) * C_ + c0;
        if (isf32) {
            float4v v0 = *(const float4v*)((const float*)x + base);
            float4v v1 = *(const float4v*)((const float*)x + base + 4);
            for (int i = 0; i < 4; i++) { xf[i] = v0[i]; xf[4 + i] = v1[i]; }
        } else {
            us8 xv = *(const us8*)((const u16*)x + base);
            for (int i = 0; i < 8; i++) xf[i] = bf2f(xv[i]);
        }
        if (r >= 4 && r < 12) {
            us8 o;
            for (int i = 0; i < 8; i++) o[i] = f2bf(xf[i]);
            *(us8*)&Hbf[base] = o;
        }
        for (int k = 0; k < KK; k++) {
            int so = r - k;
            if (so < 0 || so >= 8) continue;
            for (int i = 0; i < 8; i++) acc[so][i] += xf[i] * wf[k][i];
        }
    }
    for (int s = 0; s < 8; s++) {
        us8 o;
        for (int i = 0; i < 8; i++) o[i] = f2bf(acc[s][i]);
        *(us8*)&dwout[((size_t)(b * S_ + s0 + s)) * C_ + c0] = o;
    }
}

// ---------------- big GEMM: P[8192][1920] = A * WallT^T + bias  (swizzled LDS, XCD-chunked)
__global__ __launch_bounds__(256) void gemm_kernel(
    const u16* __restrict__ hidden, const u16* __restrict__ dwb,
    const u16* __restrict__ WallT, const float* __restrict__ bias,
    u16* __restrict__ P)
{
    __shared__ __attribute__((aligned(16))) u16 As[128 * 64];
    __shared__ __attribute__((aligned(16))) u16 Bs[128 * 64];
    int bx = blockIdx.x;
    // XCD-chunked: XCD x=bx&7 owns tm in [8x,8x+8) for all tn (A chunk 1.6MB L2-fits)
    int tm = (bx & 7) * 8 + ((bx >> 3) & 7);
    int tn = bx >> 6;
    const u16* A = (tn >= 12) ? dwb : hidden;
    int tid = threadIdx.x;
    int lane = tid & 63, wv = tid >> 6;
    int wm = wv >> 1, wn = wv & 1;
    int l15 = lane & 15, l4 = lane >> 4;
    int srow = lane >> 3;
    int swz = (((lane & 7) ^ (lane >> 3)) & 7) * 8;
    f32x4 acc[4][4] = {};
    for (int kt = 0; kt < 12; ++kt) {
        __syncthreads();
        for (int c = 0; c < 4; c++) {
            int r = wv * 32 + c * 8;
            gload16(&A[(size_t)(tm * 128 + r + srow) * C_ + kt * 64 + swz], &As[r * 64]);
            gload16(&WallT[(size_t)(tn * 128 + r + srow) * C_ + kt * 64 + swz], &Bs[r * 64]);
        }
        asm volatile("s_waitcnt vmcnt(0)" ::: "memory");
        __syncthreads();
        for (int ks = 0; ks < 2; ++ks) {
            bf16x8 aF[4], bF[4];
            for (int mi = 0; mi < 4; mi++)
                aF[mi] = *(const bf16x8*)&As[rc(wm * 64 + mi * 16 + l15, ks * 4 + l4)];
            for (int ni = 0; ni < 4; ni++)
                bF[ni] = *(const bf16x8*)&Bs[rc(wn * 64 + ni * 16 + l15, ks * 4 + l4)];
            for (int mi = 0; mi < 4; mi++)
                for (int ni = 0; ni < 4; ni++)
                    acc[mi][ni] = __builtin_amdgcn_mfma_f32_16x16x32_bf16(
                        aF[mi], bF[ni], acc[mi][ni], 0, 0, 0);
        }
    }
    for (int mi = 0; mi < 4; mi++)
        for (int ni = 0; ni < 4; ni++)
            for (int j = 0; j < 4; j++) {
                int row = tm * 128 + wm * 64 + mi * 16 + l4 * 4 + j;
                int col = tn * 128 + wn * 64 + ni * 16 + l15;
                P[(size_t)row * NW + col] = f2bf(acc[mi][ni][j] + bias[col]);
            }
}

// ---------------- V transpose via LDS tile: Vt[bh][d][s]
__global__ __launch_bounds__(256) void vt_kernel(
    const u16* __restrict__ P, u16* __restrict__ Vt)
{
    __shared__ u16 T[64][72];
    int st = blockIdx.x, bh = blockIdx.y;
    int b = bh / H_, h = bh % H_;
    int tid = threadIdx.x;
    for (int p = 0; p < 2; p++) {
        int row = p * 32 + (tid >> 3);
        int cd = (tid & 7) * 8;
        us8 v = *(const us8*)&P[(size_t)(b * S_ + st * 64 + row) * NW + 2 * AH + h * D_ + cd];
        *(us8*)&T[row][cd] = v;
    }
    __syncthreads();
    int d = tid & 63, sg = tid >> 6;
    for (int part = 0; part < 2; part++) {
        int sl = sg * 16 + part * 8;
        us8 o;
        for (int i = 0; i < 8; i++) o[i] = T[sl + i][d];
        *(us8*)&Vt[((size_t)bh * D_ + d) * S_ + st * 64 + sl] = o;
    }
}

// ---------------- flash attention: KVBLK=128 single-buffer, swizzled LDS,
//                  packed P (Q-overlay), maskless fast path, raw v_exp, defer-max
__global__ __launch_bounds__(256) void flash_kernel(
    const u16* __restrict__ P, const u16* __restrict__ Vt,
    const void* __restrict__ mask, const int* __restrict__ flag,
    void* __restrict__ out)
{
    // u16 map: [0,4608) Qs->PpS | [4608,12800) Ks 128x64 | [12800,20992) Vts 64x128 | [20992,23040) MsB
    __shared__ __attribute__((aligned(16))) u16 lds[23040];   // 46080 B -> 3 blocks/CU
    const float LOG2E = 1.4426950408889634f;

    int qt = blockIdx.x, bh = blockIdx.y;
    int b = bh / H_, h = bh % H_;
    int tid = threadIdx.x, lane = tid & 63, wvid = tid >> 6;
    int l15 = lane & 15, l4 = lane >> 4;
    int srow = lane >> 3;
    int swz = (((lane & 7) ^ (lane >> 3)) & 7) * 8;
    int vr = lane >> 4, vc = lane & 15;          // V staging: 4 rows x 16 chunks per call
    int isf32 = flag[0];
    int mnz = flag[1];
    u16* Qs  = lds;
    u16* Ks  = lds + 4608;
    u16* Vts = lds + 12800;
    u16* MsB = lds + 20992;
    unsigned* Pw = (unsigned*)lds + wvid * 576;

    {   // stage mask as bf16 (read only if mask nonzero later)
        us8 mv;
        for (int j = 0; j < 8; j++) mv[j] = f2bf(ldmix(mask, (size_t)b * S_ + tid * 8 + j, isf32));
        *(us8*)&MsB[tid * 8] = mv;
    }
    for (int c = 0; c < 2; c++) {         // stage Q tile [64 q][64 d]
        int r = wvid * 16 + c * 8;
        gload16(&P[(size_t)(b * S_ + qt * 64 + r + srow) * NW + h * D_ + swz], &Qs[r * 64]);
    }
    asm volatile("s_waitcnt vmcnt(0)" ::: "memory");
    __syncthreads();
    bf16x8 qf[2];
    for (int ks = 0; ks < 2; ks++)
        qf[ks] = *(const bf16x8*)&Qs[rc(wvid * 16 + l15, ks * 4 + l4)];
    __syncthreads();   // all qf reads done before any PpS write (PpS overlays Qs)

    f32x4 oacc[4] = {};
    float mrun = -INFINITY, lrun = 0.f;

    for (int t = 0; t < 16; ++t) {
        if (t) __syncthreads();           // prev tile's LDS reads complete before restage
        for (int c = 0; c < 4; ++c) {     // K tile: 128 rows x 64
            int kr = wvid * 32 + c * 8;
            gload16(&P[(size_t)(b * S_ + t * 128 + kr + srow) * NW + AH + h * D_ + swz],
                    &Ks[kr * 64]);
        }
        for (int c = 0; c < 4; ++c) {     // V^T tile: 64 rows x 128 (pre-swizzled source)
            int dr = wvid * 16 + c * 4;
            int row = dr + vr;
            gload16(&Vt[((size_t)bh * D_ + row) * S_ + t * 128 + ((vc ^ (row & 7)) << 3)],
                    &Vts[dr * 128]);
        }
        asm volatile("s_waitcnt vmcnt(0)" ::: "memory");
        __syncthreads();

        // S^T = K * Q^T over 128 keys: lane holds S[key = kf*16 + l4*4 + j][q = l15]
        f32x4 sacc[8] = {};
        for (int ks = 0; ks < 2; ks++)
            for (int kf = 0; kf < 8; kf++) {
                bf16x8 aK = *(const bf16x8*)&Ks[rc(kf * 16 + l15, ks * 4 + l4)];
                sacc[kf] = __builtin_amdgcn_mfma_f32_16x16x32_bf16(aK, qf[ks], sacc[kf], 0, 0, 0);
            }

        for (int hf = 0; hf < 2; ++hf) {  // two 64-key online-softmax+PV passes
            float vals[4][4];
            float tmax = -INFINITY;
            for (int kf = 0; kf < 4; kf++)
                for (int j = 0; j < 4; j++)
                    vals[kf][j] = sacc[hf * 4 + kf][j] * 0.125f;
            if (mnz) {
                for (int kf = 0; kf < 4; kf++)
                    for (int j = 0; j < 4; j++)
                        vals[kf][j] += bf2f(MsB[t * 128 + hf * 64 + kf * 16 + l4 * 4 + j]);
            }
            for (int kf = 0; kf < 4; kf++)
                for (int j = 0; j < 4; j++) tmax = fmaxf(tmax, vals[kf][j]);
            tmax = fmaxf(tmax, __shfl_xor(tmax, 16));
            tmax = fmaxf(tmax, __shfl_xor(tmax, 32));
            if (!__all(tmax - mrun <= 8.0f)) {      // defer-max (THR=8)
                float mnew = fmaxf(mrun, tmax);
                float alpha = __builtin_amdgcn_exp2f((mrun - mnew) * LOG2E);
                lrun *= alpha;
                for (int mf = 0; mf < 4; mf++) oacc[mf] *= alpha;
                mrun = mnew;
            }
            float ps = 0.f;
            for (int kf = 0; kf < 4; kf++) {
                float p0 = __builtin_amdgcn_exp2f((vals[kf][0] - mrun) * LOG2E);
                float p1 = __builtin_amdgcn_exp2f((vals[kf][1] - mrun) * LOG2E);
                float p2 = __builtin_amdgcn_exp2f((vals[kf][2] - mrun) * LOG2E);
                float p3 = __builtin_amdgcn_exp2f((vals[kf][3] - mrun) * LOG2E);
                ps += (p0 + p1) + (p2 + p3);
                union { float f; unsigned u; } b0{p0}, b1{p1}, b2{p2}, b3{p3};
                unsigned w0 = (b0.u >> 16) | (b1.u & 0xffff0000u);
                unsigned w1 = (b2.u >> 16) | (b3.u & 0xffff0000u);
                unsigned idx = l15 * 36 + kf * 8 + l4 * 2;
                Pw[idx] = w0;
                Pw[idx + 1] = w1;
            }
            ps += __shfl_xor(ps, 16);
            ps += __shfl_xor(ps, 32);
            lrun += ps;
            asm volatile("s_waitcnt lgkmcnt(0)" ::: "memory");
            __builtin_amdgcn_sched_barrier(0);

            // O^T += V^T * P^T  (V chunks hf*8 + ks2*4 + l4 select keys hf*64 + ks2*32..)
            for (int ks2 = 0; ks2 < 2; ks2++) {
                bf16x8 pf = *(const bf16x8*)&Pw[l15 * 36 + ks2 * 16 + l4 * 4];
                for (int mf = 0; mf < 4; mf++) {
                    bf16x8 av = *(const bf16x8*)&Vts[rc128(mf * 16 + l15, hf * 8 + ks2 * 4 + l4)];
                    oacc[mf] = __builtin_amdgcn_mfma_f32_16x16x32_bf16(av, pf, oacc[mf], 0, 0, 0);
                }
            }
        }
    }
    float rinv = 1.0f / lrun;
    int tok = qt * 64 + wvid * 16 + l15;
    for (int mf = 0; mf < 4; mf++)
        for (int j = 0; j < 4; j++) {
            int d = mf * 16 + l4 * 4 + j;
            size_t oi = (size_t)(b * S_ + tok) * C_ + h * D_ + d;
            float val = oacc[mf][j] * rinv;
            if (isf32) ((float*)out)[oi] = val; else ((u16*)out)[oi] = f2bf(val);
        }
}

// ---------------- dynamic-kernel logits: L[8192][64] = (q .* key_conv) @ WckT^T + bck  (MFMA)
__global__ __launch_bounds__(256) void dynlogit_kernel(
    const u16* __restrict__ P, const u16* __restrict__ WckT,
    const float* __restrict__ bckc, float* __restrict__ L)
{
    __shared__ __attribute__((aligned(16))) u16 As[64 * 64];
    __shared__ __attribute__((aligned(16))) u16 Bs[64 * 64];
    int tok0 = blockIdx.x * 64;
    int tid = threadIdx.x;
    int lane = tid & 63, w = tid >> 6;
    int l15 = lane & 15, l4 = lane >> 4;
    int srow = lane >> 3;
    int swz = (((lane & 7) ^ (lane >> 3)) & 7) * 8;
    int ar = tid >> 2;
    int ac0 = (tid & 3) * 16;
    f32x4 acc[4] = {};
    for (int kt = 0; kt < 6; ++kt) {
        __syncthreads();
        for (int c = 0; c < 2; c++) {
            int r = w * 16 + c * 8;
            gload16(&WckT[(size_t)(r + srow) * AH + kt * 64 + swz], &Bs[r * 64]);
        }
        {
            size_t base = (size_t)(tok0 + ar) * NW + kt * 64 + ac0;
            us8 qv0 = *(const us8*)&P[base];
            us8 qv1 = *(const us8*)&P[base + 8];
            us8 kv0 = *(const us8*)&P[base + 4 * AH];
            us8 kv1 = *(const us8*)&P[base + 4 * AH + 8];
            us8 o0, o1;
            for (int i = 0; i < 8; i++) {
                o0[i] = f2bf(bf2f(qv0[i]) * bf2f(kv0[i]));
                o1[i] = f2bf(bf2f(qv1[i]) * bf2f(kv1[i]));
            }
            int cb = ac0 >> 3;
            *(us8*)&As[rc(ar, cb)] = o0;
            *(us8*)&As[rc(ar, cb + 1)] = o1;
        }
        asm volatile("s_waitcnt vmcnt(0)" ::: "memory");
        __syncthreads();
        for (int ks = 0; ks < 2; ++ks) {
            bf16x8 aF = *(const bf16x8*)&As[rc(w * 16 + l15, ks * 4 + l4)];
            for (int ni = 0; ni < 4; ni++) {
                bf16x8 bF = *(const bf16x8*)&Bs[rc(ni * 16 + l15, ks * 4 + l4)];
                acc[ni] = __builtin_amdgcn_mfma_f32_16x16x32_bf16(aF, bF, acc[ni], 0, 0, 0);
            }
        }
    }
    for (int j = 0; j < 4; j++) {
        int tok = tok0 + w * 16 + l4 * 4 + j;
        for (int ni = 0; ni < 4; ni++) {
            int col = ni * 16 + l15;
            if (col < NCK) L[(size_t)tok * 64 + col] = acc[ni][j] + bckc[col];
        }
    }
}

// ---------------- dynamic conv context: softmax(9) + window MAC, thread per 8 channels
__global__ __launch_bounds__(256) void dynctx_kernel(
    const u16* __restrict__ P, const float* __restrict__ L,
    const int* __restrict__ flag, void* __restrict__ out)
{
    const float LOG2E = 1.4426950408889634f;
    int idx = blockIdx.x * 256 + threadIdx.x;
    int g = idx % 48, tok = idx / 48;
    int ch0 = g * 8, h = ch0 >> 6;
    int s = tok & (S_ - 1);
    int isf32 = flag[0];
    float lg[KK];
    float m = -INFINITY;
    for (int k = 0; k < KK; k++) {
        lg[k] = L[(size_t)tok * 64 + h * KK + k];
        m = fmaxf(m, lg[k]);
    }
    float ssum = 0.f;
    for (int k = 0; k < KK; k++) {
        lg[k] = __builtin_amdgcn_exp2f((lg[k] - m) * LOG2E);
        ssum += lg[k];
    }
    float sinv = 1.0f / ssum;
    float acc[8];
    for (int i = 0; i < 8; i++) acc[i] = 0.f;
    for (int k = 0; k < KK; k++) {
        int ss = s + k - 4;
        if (ss < 0 || ss >= S_) continue;
        us8 v = *(const us8*)&P[(size_t)(tok + k - 4) * NW + 3 * AH + ch0];
        float kw = lg[k] * sinv;
        for (int i = 0; i < 8; i++) acc[i] = fmaf(kw, bf2f(v[i]), acc[i]);
    }
    size_t oi = (size_t)tok * C_ + AH + ch0;
    if (isf32) {
        float4v o0, o1;
        for (int i = 0; i < 4; i++) { o0[i] = acc[i]; o1[i] = acc[4 + i]; }
        *(float4v*)((float*)out + oi) = o0;
        *(float4v*)((float*)out + oi + 4) = o1;
    } else {
        us8 o;
        for (int i = 0; i < 8; i++) o[i] = f2bf(acc[i]);
        *(us8*)((u16*)out + oi) = o;
    }
}

extern "C" void kernel_launch(void* const* d_in, const int* in_sizes, int n_in,
                              void* d_out, int out_size, void* d_ws, size_t ws_size,
                              hipStream_t stream) {
    const void* hidden = d_in[0];
    const void* mask   = d_in[1];
    const void* Wq  = d_in[2];
    const void* bq  = d_in[3];
    const void* Wk  = d_in[4];
    const void* bk  = d_in[5];
    const void* Wv  = d_in[6];
    const void* bv  = d_in[7];
    const void* dwk = d_in[8];
    const void* pw  = d_in[9];
    const void* cb  = d_in[10];
    const void* Wck = d_in[11];
    const void* bck = d_in[12];
    const void* Wco = d_in[13];
    const void* bco = d_in[14];
    char* ws = (char*)d_ws;

    const size_t NEED = 65934608u;
    if (ws_size < NEED) return;

    u16*   Pbuf  = (u16*)(ws);                       // 31,457,280
    u16*   Hbf   = (u16*)(ws + 31457280);            // 12,582,912 (L aliases this after gemm)
    u16*   dwb   = (u16*)(ws + 44040192);            // 12,582,912
    u16*   WallT = (u16*)(ws + 56623104);            //  2,949,120
    float* bias  = (float*)(ws + 59572224);          //      7,680
    u16*   Vt    = (u16*)(ws + 59579904);            //  6,291,456
    u16*   dwkc  = (u16*)(ws + 65871360);            //     13,824
    u16*   WckT  = (u16*)(ws + 65885184);            //     49,152 = 64*AH*2
    float* bckc  = (float*)(ws + 65934336);          //        256
    int*   flag  = (int*)(ws + 65934592);            //         16
    float* Lbuf  = (float*)Hbf;                      //  2,097,152 (alias)

    sniff_kernel<<<1, 1024, 0, stream>>>((const unsigned*)hidden, flag);
    canon_kernel<<<156, 256, 0, stream>>>(dwk, Wck, bck, mask, flag, dwkc, WckT, bckc);
    prep_kernel<<<720, 256, 0, stream>>>(Wq, Wk, Wv, Wco, pw, bq, bk, bv, bco, cb, flag, WallT, bias);
    dwconv_kernel<<<384, 256, 0, stream>>>(hidden, dwkc, flag, Hbf, dwb);
    gemm_kernel<<<960, 256, 0, stream>>>(Hbf, dwb, WallT, bias, Pbuf);
    vt_kernel<<<dim3(32, 24), 256, 0, stream>>>(Pbuf, Vt);
    dynlogit_kernel<<<128, 256, 0, stream>>>(Pbuf, WckT, bckc, Lbuf);
    flash_kernel<<<dim3(32, 24), 256, 0, stream>>>(Pbuf, Vt, mask, flag, d_out);
    dynctx_kernel<<<1536, 256, 0, stream>>>(Pbuf, Lbuf, flag, d_out);
}